// Round 7
// baseline (2598.570 us; speedup 1.0000x reference)
//
#include <hip/hip_runtime.h>
#include <hip/hip_bf16.h>
#include <cstdint>

// Problem constants
constexpr int BB = 64;    // batch
constexpr int TT = 12;    // time
constexpr int NN = 512;   // nodes
constexpr int FF = 64;    // features
constexpr int UU = 64;    // units
constexpr int MAXNZ = 128;
constexpr int MCH = 16;   // m-columns per k_product_E block

// ---------------------------------------------------------------------------
// Workspace layout (bytes):
//   floats: lhs 0 / rhs 393216f / beT 786432f / evals 1048576f (see R0)
//   ints:   nnz 20971520 / cidx 20973568 / ccnt 21235712 / colj 21237760
//   KT  (U,F) fp32 : 21499904, 16384 B
//   xb16(B,T,N,F)  : 21516288, 50331648 B   (bf16 copy of x, if ws allows)
// ---------------------------------------------------------------------------
constexpr size_t OF_LHS   = 0;
constexpr size_t OF_RHS   = 393216;
constexpr size_t OF_BET   = 786432;
constexpr size_t OF_EVALS = 1048576;
constexpr size_t OB_NNZ   = 20971520;
constexpr size_t OB_CIDX  = 20973568;
constexpr size_t OB_CCNT  = 21235712;
constexpr size_t OB_COLJ  = 21237760;
constexpr size_t OB_KT    = 21499904;
constexpr size_t OB_XB16  = 21516288;
constexpr size_t XB16_BYTES = (size_t)BB * TT * NN * FF * 2;  // 50331648

__device__ __forceinline__ float wred_sum(float v) {
  #pragma unroll
  for (int off = 32; off; off >>= 1) v += __shfl_xor(v, off, 64);
  return v;
}

// ---------------------------------------------------------------------------
// Kernel 1: lhs/rhs as before; optionally also writes bf16 copy of x
// (each x element is touched exactly once here: unit=(b,n), lane=f, t-loop).
// ---------------------------------------------------------------------------
__global__ __launch_bounds__(256) void k_lhs_rhs(
    const float* __restrict__ x, const float* __restrict__ W1,
    const float* __restrict__ W2, const float* __restrict__ W3,
    float* __restrict__ lhs, float* __restrict__ rhsS,
    unsigned short* __restrict__ xb16)   // may be null
{
  int unit = blockIdx.x * 4 + (threadIdx.x >> 6);   // b*512 + n
  int lane = threadIdx.x & 63;
  int b = unit >> 9, n = unit & 511;

  const float* xb = x + ((size_t)b * TT * NN + n) * FF + lane;
  float xv[12];
  #pragma unroll
  for (int t = 0; t < 12; ++t) xv[t] = xb[(size_t)t * NN * FF];

  if (xb16) {
    unsigned short* xo = xb16 + ((size_t)b * TT * NN + n) * FF + lane;
    #pragma unroll
    for (int t = 0; t < 12; ++t) {
      __hip_bfloat16 h = __float2bfloat16(xv[t]);   // RTNE
      xo[(size_t)t * NN * FF] = *reinterpret_cast<unsigned short*>(&h);
    }
  }

  float r1 = 0.f;
  #pragma unroll
  for (int t = 0; t < 12; ++t) r1 += xv[t] * W1[t];

  float w3 = W3[lane];

  float myl = 0.f, myr = 0.f;
  #pragma unroll
  for (int t = 0; t < 12; ++t) {
    float a = r1 * W2[lane * 12 + t];
    float c = xv[t] * w3;
    a = wred_sum(a);
    c = wred_sum(c);
    if (lane == t) { myl = a; myr = c; }
  }
  if (lane < 12) {
    lhs[(size_t)unit * 12 + lane]  = myl;
    rhsS[(size_t)unit * 12 + lane] = myr;
  }
}

// ---------------------------------------------------------------------------
// Kernel 2: beT[m,k] = be[k,m]; last block also builds KT[u,f] = K[f,u]
// ---------------------------------------------------------------------------
__global__ __launch_bounds__(256) void k_transpose(
    const float* __restrict__ be, float* __restrict__ beT,
    const float* __restrict__ K, float* __restrict__ KT)
{
  if (blockIdx.x == NN * NN / 256) {
    for (int i = threadIdx.x; i < UU * FF; i += 256) {
      int u = i >> 6, f = i & 63;
      KT[u * 64 + f] = K[f * 64 + u];
    }
    return;
  }
  int i = blockIdx.x * 256 + threadIdx.x;  // 262144 total
  int k = i >> 9, m = i & 511;
  beT[m * 512 + k] = be[i];
}

// ---------------------------------------------------------------------------
// Kernel 3: row-wise compaction of mask A (deterministic, ordered by m)
// ---------------------------------------------------------------------------
__global__ void k_build_idx(const float* __restrict__ A,
                            int* __restrict__ nnz, int* __restrict__ cidx)
{
  int j = blockIdx.x;
  int lane = threadIdx.x;  // 64 threads
  unsigned long long lt = (1ull << lane) - 1ull;
  int base = 0;
  for (int c = 0; c < 8; ++c) {
    int m = c * 64 + lane;
    bool p = A[(size_t)j * 512 + m] > 0.5f;
    unsigned long long mask = __ballot(p);
    int pos = base + __popcll(mask & lt);
    if (p && pos < MAXNZ) cidx[j * MAXNZ + pos] = m;
    base += __popcll(mask);
  }
  if (lane == 0) nnz[j] = base > MAXNZ ? MAXNZ : base;
}

// ---------------------------------------------------------------------------
// Kernel 4: column lists
// ---------------------------------------------------------------------------
__global__ void k_build_col(const int* __restrict__ nnz, const int* __restrict__ cidx,
                            int* __restrict__ ccnt, unsigned* __restrict__ colj)
{
  int j = blockIdx.x;
  int lane = threadIdx.x;
  int cnt = nnz[j];
  for (int s = lane; s < cnt; s += 64) {
    int m = cidx[j * MAXNZ + s];
    int pos = atomicAdd(&ccnt[m], 1);
    if (pos < MAXNZ) colj[m * MAXNZ + pos] = (unsigned)j | ((unsigned)s << 16);
  }
}

// ---------------------------------------------------------------------------
// Kernel 5 (v2): unchanged (16 columns/block, 16-lane entry groups)
// ---------------------------------------------------------------------------
__global__ __launch_bounds__(256) void k_product_E(
    const float* __restrict__ lhs, const float* __restrict__ rhsS,
    const float* __restrict__ beT, const float* __restrict__ Ve,
    const int* __restrict__ ccnt, const unsigned* __restrict__ colj,
    float* __restrict__ evals)
{
  int b  = blockIdx.x;   // 0..63
  int mc = blockIdx.y;   // 0..31

  __shared__ float lhsL[512 * 13];  // stride 13: conflict-free
  __shared__ float sL[4][512];
  __shared__ float rh[MCH * 12];

  int tid = threadIdx.x;
  const float* src = lhs + (size_t)b * 512 * 12;
  for (int i = tid; i < 6144; i += 256) {
    int k = i / 12, t = i - k * 12;
    lhsL[k * 13 + t] = src[i];
  }
  if (tid < MCH * 12) rh[tid] = rhsS[((size_t)b * 512 + mc * MCH) * 12 + tid];
  __syncthreads();

  int wave = tid >> 6, lane = tid & 63;
  int grp = lane >> 4, lg = lane & 15;

  for (int g = 0; g < MCH / 4; ++g) {
    if (g) __syncthreads();
    for (int i = tid; i < 4 * 512; i += 256) {
      int w = i >> 9, k = i & 511;
      int m = mc * MCH + g * 4 + w;
      float p = beT[m * 512 + k];
      const float* lr = &lhsL[k * 13];
      const float* rw = &rh[(g * 4 + w) * 12];
      #pragma unroll
      for (int t = 0; t < 12; ++t) p += lr[t] * rw[t];
      sL[w][k] = 1.0f / (1.0f + __expf(-p));
    }
    __syncthreads();

    int m = mc * MCH + g * 4 + wave;
    int cnt = ccnt[m];
    if (cnt > MAXNZ) cnt = MAXNZ;
    const float* sw = sL[wave];
    for (int e = grp; e < cnt; e += 4) {
      unsigned pk = colj[m * MAXNZ + e];
      int j = pk & 0xffff, slot = (int)(pk >> 16);
      const float* vr = Ve + (size_t)j * 512;
      float part = 0.f;
      #pragma unroll
      for (int kk = 0; kk < 32; ++kk)
        part = fmaf(vr[kk * 16 + lg], sw[kk * 16 + lg], part);
      #pragma unroll
      for (int off = 8; off; off >>= 1) part += __shfl_xor(part, off, 64);
      if (lg == 0) evals[((size_t)b * 512 + j) * MAXNZ + slot] = part;
    }
  }
}

// ---------------------------------------------------------------------------
// Kernel 6: masked softmax (unchanged)
// ---------------------------------------------------------------------------
__global__ __launch_bounds__(256) void k_softmax(
    const int* __restrict__ nnz, float* __restrict__ evals)
{
  int unit = blockIdx.x * 4 + (threadIdx.x >> 6);  // b*512 + j
  int lane = threadIdx.x & 63;
  int j = unit & 511;
  int cnt = nnz[j];
  float* ev = evals + (size_t)unit * MAXNZ;
  float v0 = lane < cnt        ? ev[lane]      : -__builtin_inff();
  float v1 = (lane + 64) < cnt ? ev[lane + 64] : -__builtin_inff();
  float mx = fmaxf(v0, v1);
  #pragma unroll
  for (int off = 32; off; off >>= 1) mx = fmaxf(mx, __shfl_xor(mx, off, 64));
  float e0 = lane < cnt        ? __expf(v0 - mx) : 0.f;
  float e1 = (lane + 64) < cnt ? __expf(v1 - mx) : 0.f;
  float s = wred_sum(e0 + e1);
  float inv = 1.0f / s;
  if (lane < cnt)        ev[lane]      = e0 * inv;
  if ((lane + 64) < cnt) ev[lane + 64] = e1 * inv;
}

// ---------------------------------------------------------------------------
// Kernel 7 (v6, bf16 gather): wave per (b,j).
//   Phase A: lane = (s4 = lane>>4 neighbor-slot, f4 = lane&15). Per neighbor
//   quad: 12 uint2 loads (8 B/lane bf16) -> HALF the L2 bytes of v5.
//   Unpack bf16->f32 via shift/and (exact), fp32 accumulate.
//   Phase B: KT (transposed K in ws) -> lane u's column = 16 coalesced
//   float4 loads (vs 64 stride-256B scalars); remat, if any, is 4x cheaper.
// XCD swizzle: grid = 8192, sbid = (bid&7)*1024 + (bid>>3) bijective.
// ---------------------------------------------------------------------------
__device__ __forceinline__ float bflo(unsigned u) {
  unsigned v = u << 16; return *reinterpret_cast<float*>(&v);
}
__device__ __forceinline__ float bfhi(unsigned u) {
  unsigned v = u & 0xFFFF0000u; return *reinterpret_cast<float*>(&v);
}

__global__ __launch_bounds__(256) void k_out6(
    const unsigned short* __restrict__ xb16,
    const int* __restrict__ nnz, const int* __restrict__ cidx,
    const float* __restrict__ evals,
    const float* __restrict__ KT, const float* __restrict__ bias,
    float* __restrict__ out)
{
  int tid = threadIdx.x;
  int wv = tid >> 6, lane = tid & 63;
  int bid = blockIdx.x;
  int sbid = (bid & 7) * 1024 + (bid >> 3);  // bijective on [0,8192)
  int unit = sbid * 4 + wv;                  // b*512 + j
  int b = unit >> 9, j = unit & 511;

  __shared__ float convL[4][12][64];   // 12 KB
  __shared__ float valL[4][MAXNZ];     //  2 KB
  __shared__ int   idxL[4][MAXNZ];     //  2 KB

  int cnt = nnz[j];
  int cnt4 = (cnt + 3) & ~3;
  for (int s = lane; s < cnt; s += 64) {
    idxL[wv][s] = cidx[j * MAXNZ + s];
    valL[wv][s] = evals[(size_t)unit * MAXNZ + s];
  }
  for (int s = cnt + lane; s < cnt4; s += 64) {
    idxL[wv][s] = 0;
    valL[wv][s] = 0.f;
  }

  int s4 = lane >> 4, f4 = lane & 15;

  float4 acc[12];
  #pragma unroll
  for (int t = 0; t < 12; ++t) acc[t] = make_float4(0.f, 0.f, 0.f, 0.f);

  const unsigned short* xbase = xb16 + (size_t)b * TT * NN * FF;
  for (int sq = 0; sq < cnt4; sq += 4) {
    int   k = idxL[wv][sq + s4];
    float v = valL[wv][sq + s4];
    const unsigned short* xk = xbase + (size_t)k * FF + f4 * 4;
    #pragma unroll
    for (int t = 0; t < 12; ++t) {
      uint2 u = *reinterpret_cast<const uint2*>(xk + (size_t)t * NN * FF);
      acc[t].x = fmaf(v, bflo(u.x), acc[t].x);
      acc[t].y = fmaf(v, bfhi(u.x), acc[t].y);
      acc[t].z = fmaf(v, bflo(u.y), acc[t].z);
      acc[t].w = fmaf(v, bfhi(u.y), acc[t].w);
    }
  }

  // combine the 4 neighbor groups (lanes differ in bits 4,5)
  #pragma unroll
  for (int t = 0; t < 12; ++t) {
    float4 a = acc[t];
    a.x += __shfl_xor(a.x, 16, 64); a.y += __shfl_xor(a.y, 16, 64);
    a.z += __shfl_xor(a.z, 16, 64); a.w += __shfl_xor(a.w, 16, 64);
    a.x += __shfl_xor(a.x, 32, 64); a.y += __shfl_xor(a.y, 32, 64);
    a.z += __shfl_xor(a.z, 32, 64); a.w += __shfl_xor(a.w, 32, 64);
    if (s4 == 0) *(float4*)&convL[wv][t][f4 * 4] = a;
  }

  const float4* kt4 = (const float4*)(KT + lane * 64);
  float bs = bias[lane];
  __syncthreads();

  #pragma unroll
  for (int t = 0; t < 12; ++t) {
    const float4* cv = (const float4*)convL[wv][t];
    float o = bs;
    #pragma unroll
    for (int i = 0; i < 16; ++i) {
      float4 c4 = cv[i];
      float4 k4 = kt4[i];
      o += c4.x * k4.x + c4.y * k4.y + c4.z * k4.z + c4.w * k4.w;
    }
    out[((size_t)(b * TT + t) * NN + j) * UU + lane] = o;
  }
}

// ---------------------------------------------------------------------------
// Kernel 7 fallback (fp32 gather, KT phase B) — used if ws too small for xb16
// ---------------------------------------------------------------------------
__global__ __launch_bounds__(256) void k_out6f(
    const float* __restrict__ x,
    const int* __restrict__ nnz, const int* __restrict__ cidx,
    const float* __restrict__ evals,
    const float* __restrict__ KT, const float* __restrict__ bias,
    float* __restrict__ out)
{
  int tid = threadIdx.x;
  int wv = tid >> 6, lane = tid & 63;
  int bid = blockIdx.x;
  int sbid = (bid & 7) * 1024 + (bid >> 3);
  int unit = sbid * 4 + wv;
  int b = unit >> 9, j = unit & 511;

  __shared__ float convL[4][12][64];
  __shared__ float valL[4][MAXNZ];
  __shared__ int   idxL[4][MAXNZ];

  int cnt = nnz[j];
  int cnt4 = (cnt + 3) & ~3;
  for (int s = lane; s < cnt; s += 64) {
    idxL[wv][s] = cidx[j * MAXNZ + s];
    valL[wv][s] = evals[(size_t)unit * MAXNZ + s];
  }
  for (int s = cnt + lane; s < cnt4; s += 64) { idxL[wv][s] = 0; valL[wv][s] = 0.f; }

  int s4 = lane >> 4, f4 = lane & 15;
  float4 acc[12];
  #pragma unroll
  for (int t = 0; t < 12; ++t) acc[t] = make_float4(0.f, 0.f, 0.f, 0.f);

  const float* xb = x + (size_t)b * TT * NN * FF;
  for (int sq = 0; sq < cnt4; sq += 4) {
    int   k = idxL[wv][sq + s4];
    float v = valL[wv][sq + s4];
    const float4* xk4 = (const float4*)(xb + (size_t)k * FF) + f4;
    #pragma unroll
    for (int t = 0; t < 12; ++t) {
      float4 xv = xk4[t * (NN * FF / 4)];
      acc[t].x = fmaf(v, xv.x, acc[t].x);
      acc[t].y = fmaf(v, xv.y, acc[t].y);
      acc[t].z = fmaf(v, xv.z, acc[t].z);
      acc[t].w = fmaf(v, xv.w, acc[t].w);
    }
  }
  #pragma unroll
  for (int t = 0; t < 12; ++t) {
    float4 a = acc[t];
    a.x += __shfl_xor(a.x, 16, 64); a.y += __shfl_xor(a.y, 16, 64);
    a.z += __shfl_xor(a.z, 16, 64); a.w += __shfl_xor(a.w, 16, 64);
    a.x += __shfl_xor(a.x, 32, 64); a.y += __shfl_xor(a.y, 32, 64);
    a.z += __shfl_xor(a.z, 32, 64); a.w += __shfl_xor(a.w, 32, 64);
    if (s4 == 0) *(float4*)&convL[wv][t][f4 * 4] = a;
  }

  const float4* kt4 = (const float4*)(KT + lane * 64);
  float bs = bias[lane];
  __syncthreads();

  #pragma unroll
  for (int t = 0; t < 12; ++t) {
    const float4* cv = (const float4*)convL[wv][t];
    float o = bs;
    #pragma unroll
    for (int i = 0; i < 16; ++i) {
      float4 c4 = cv[i];
      float4 k4 = kt4[i];
      o += c4.x * k4.x + c4.y * k4.y + c4.z * k4.z + c4.w * k4.w;
    }
    out[((size_t)(b * TT + t) * NN + j) * UU + lane] = o;
  }
}

// ---------------------------------------------------------------------------
extern "C" void kernel_launch(void* const* d_in, const int* in_sizes, int n_in,
                              void* d_out, int out_size, void* d_ws, size_t ws_size,
                              hipStream_t stream)
{
  const float* x    = (const float*)d_in[0];  // (B,T,N,F)
  const float* A    = (const float*)d_in[1];  // (N,N)
  const float* W1   = (const float*)d_in[2];  // (T,1)
  const float* W2   = (const float*)d_in[3];  // (F,T)
  const float* W3   = (const float*)d_in[4];  // (F,1)
  const float* Ve   = (const float*)d_in[5];  // (N,N)
  const float* be   = (const float*)d_in[6];  // (N,N)
  const float* K    = (const float*)d_in[7];  // (F,U)
  const float* bias = (const float*)d_in[8];  // (U,)
  float* out = (float*)d_out;

  char* ws = (char*)d_ws;
  float* lhs   = (float*)ws + OF_LHS;
  float* rhsS  = (float*)ws + OF_RHS;
  float* beT   = (float*)ws + OF_BET;
  float* evals = (float*)ws + OF_EVALS;
  int*      nnz  = (int*)(ws + OB_NNZ);
  int*      cidx = (int*)(ws + OB_CIDX);
  int*      ccnt = (int*)(ws + OB_CCNT);
  unsigned* colj = (unsigned*)(ws + OB_COLJ);
  float*    KT   = (float*)(ws + OB_KT);
  unsigned short* xb16 = (unsigned short*)(ws + OB_XB16);

  const bool use_bf16 = ws_size >= OB_XB16 + XB16_BYTES;

  hipMemsetAsync(ccnt, 0, NN * sizeof(int), stream);

  // 1. lhs / rhs (+ bf16 copy of x when ws allows)
  k_lhs_rhs<<<dim3(BB * NN / 4), dim3(256), 0, stream>>>(
      x, W1, W2, W3, lhs, rhsS, use_bf16 ? xb16 : nullptr);
  // 2. transpose be (+ KT)
  k_transpose<<<dim3(NN * NN / 256 + 1), dim3(256), 0, stream>>>(be, beT, K, KT);
  // 3. row index lists
  k_build_idx<<<dim3(NN), dim3(64), 0, stream>>>(A, nnz, cidx);
  // 4. column lists
  k_build_col<<<dim3(NN), dim3(64), 0, stream>>>(nnz, cidx, ccnt, colj);
  // 5. product + sigmoid + masked E
  k_product_E<<<dim3(BB, NN / MCH), dim3(256), 0, stream>>>(lhs, rhsS, beT, Ve, ccnt, colj, evals);
  // 6. softmax over slots
  k_softmax<<<dim3(BB * NN / 4), dim3(256), 0, stream>>>(nnz, evals);
  // 7. sparse conv + output GEMM
  if (use_bf16)
    k_out6<<<dim3(BB * NN / 4), dim3(256), 0, stream>>>(xb16, nnz, cidx, evals, KT, bias, out);
  else
    k_out6f<<<dim3(BB * NN / 4), dim3(256), 0, stream>>>(x, nnz, cidx, evals, KT, bias, out);
}

// Round 8
// 2573.764 us; speedup vs baseline: 1.0096x; 1.0096x over previous
//
#include <hip/hip_runtime.h>
#include <hip/hip_bf16.h>
#include <cstdint>

// Problem constants
constexpr int BB = 64;    // batch
constexpr int TT = 12;    // time
constexpr int NN = 512;   // nodes
constexpr int FF = 64;    // features
constexpr int UU = 64;    // units
constexpr int MAXNZ = 128;
constexpr int MCH = 16;   // m-columns per k_product_E block

// ---------------------------------------------------------------------------
// Workspace layout (bytes):
//   floats: lhs 0 / rhs 393216f / beT 786432f / evals 1048576f
//   ints:   nnz 20971520 / cidx 20973568 / ccnt 21235712 / colj 21237760
//   KT  (U,F) fp32 : 21499904, 16384 B
//   xT  (B,N,T,F) bf16 : 21516288, 50331648 B  (transposed copy; R7 proved fit)
// ---------------------------------------------------------------------------
constexpr size_t OF_LHS   = 0;
constexpr size_t OF_RHS   = 393216;
constexpr size_t OF_BET   = 786432;
constexpr size_t OF_EVALS = 1048576;
constexpr size_t OB_NNZ   = 20971520;
constexpr size_t OB_CIDX  = 20973568;
constexpr size_t OB_CCNT  = 21235712;
constexpr size_t OB_COLJ  = 21237760;
constexpr size_t OB_KT    = 21499904;
constexpr size_t OB_XT    = 21516288;
constexpr size_t XT_BYTES = (size_t)BB * NN * TT * FF * 2;  // 50331648

__device__ __forceinline__ float wred_sum(float v) {
  #pragma unroll
  for (int off = 32; off; off >>= 1) v += __shfl_xor(v, off, 64);
  return v;
}

__device__ __forceinline__ float bflo(unsigned u) {
  unsigned v = u << 16; return *reinterpret_cast<float*>(&v);
}
__device__ __forceinline__ float bfhi(unsigned u) {
  unsigned v = u & 0xFFFF0000u; return *reinterpret_cast<float*>(&v);
}

// ---------------------------------------------------------------------------
// Kernel 1: lhs/rhs reductions; also writes xT[b][n][t][f] (bf16 transposed
// copy of x) if requested — xv[12] is already register-resident here.
// ---------------------------------------------------------------------------
__global__ __launch_bounds__(256) void k_lhs_rhs(
    const float* __restrict__ x, const float* __restrict__ W1,
    const float* __restrict__ W2, const float* __restrict__ W3,
    float* __restrict__ lhs, float* __restrict__ rhsS,
    unsigned short* __restrict__ xT)   // may be null
{
  int unit = blockIdx.x * 4 + (threadIdx.x >> 6);   // b*512 + n
  int lane = threadIdx.x & 63;
  int b = unit >> 9, n = unit & 511;

  const float* xb = x + ((size_t)b * TT * NN + n) * FF + lane;
  float xv[12];
  #pragma unroll
  for (int t = 0; t < 12; ++t) xv[t] = xb[(size_t)t * NN * FF];

  if (xT) {
    unsigned short* xo = xT + (size_t)unit * (TT * FF) + lane;
    #pragma unroll
    for (int t = 0; t < 12; ++t) {
      __hip_bfloat16 h = __float2bfloat16(xv[t]);   // RTNE
      xo[t * FF] = *reinterpret_cast<unsigned short*>(&h);  // 128 B/instr
    }
  }

  float r1 = 0.f;
  #pragma unroll
  for (int t = 0; t < 12; ++t) r1 += xv[t] * W1[t];

  float w3 = W3[lane];

  float myl = 0.f, myr = 0.f;
  #pragma unroll
  for (int t = 0; t < 12; ++t) {
    float a = r1 * W2[lane * 12 + t];
    float c = xv[t] * w3;
    a = wred_sum(a);
    c = wred_sum(c);
    if (lane == t) { myl = a; myr = c; }
  }
  if (lane < 12) {
    lhs[(size_t)unit * 12 + lane]  = myl;
    rhsS[(size_t)unit * 12 + lane] = myr;
  }
}

// ---------------------------------------------------------------------------
// Kernel 2: beT[m,k] = be[k,m]; last block also builds KT[u,f] = K[f,u]
// ---------------------------------------------------------------------------
__global__ __launch_bounds__(256) void k_transpose(
    const float* __restrict__ be, float* __restrict__ beT,
    const float* __restrict__ K, float* __restrict__ KT)
{
  if (blockIdx.x == NN * NN / 256) {
    for (int i = threadIdx.x; i < UU * FF; i += 256) {
      int u = i >> 6, f = i & 63;
      KT[u * 64 + f] = K[f * 64 + u];
    }
    return;
  }
  int i = blockIdx.x * 256 + threadIdx.x;  // 262144 total
  int k = i >> 9, m = i & 511;
  beT[m * 512 + k] = be[i];
}

// ---------------------------------------------------------------------------
// Kernel 3: row-wise compaction of mask A (deterministic, ordered by m)
// ---------------------------------------------------------------------------
__global__ void k_build_idx(const float* __restrict__ A,
                            int* __restrict__ nnz, int* __restrict__ cidx)
{
  int j = blockIdx.x;
  int lane = threadIdx.x;  // 64 threads
  unsigned long long lt = (1ull << lane) - 1ull;
  int base = 0;
  for (int c = 0; c < 8; ++c) {
    int m = c * 64 + lane;
    bool p = A[(size_t)j * 512 + m] > 0.5f;
    unsigned long long mask = __ballot(p);
    int pos = base + __popcll(mask & lt);
    if (p && pos < MAXNZ) cidx[j * MAXNZ + pos] = m;
    base += __popcll(mask);
  }
  if (lane == 0) nnz[j] = base > MAXNZ ? MAXNZ : base;
}

// ---------------------------------------------------------------------------
// Kernel 4: column lists
// ---------------------------------------------------------------------------
__global__ void k_build_col(const int* __restrict__ nnz, const int* __restrict__ cidx,
                            int* __restrict__ ccnt, unsigned* __restrict__ colj)
{
  int j = blockIdx.x;
  int lane = threadIdx.x;
  int cnt = nnz[j];
  for (int s = lane; s < cnt; s += 64) {
    int m = cidx[j * MAXNZ + s];
    int pos = atomicAdd(&ccnt[m], 1);
    if (pos < MAXNZ) colj[m * MAXNZ + pos] = (unsigned)j | ((unsigned)s << 16);
  }
}

// ---------------------------------------------------------------------------
// Kernel 5 (v2): unchanged (16 columns/block, 16-lane entry groups)
// ---------------------------------------------------------------------------
__global__ __launch_bounds__(256) void k_product_E(
    const float* __restrict__ lhs, const float* __restrict__ rhsS,
    const float* __restrict__ beT, const float* __restrict__ Ve,
    const int* __restrict__ ccnt, const unsigned* __restrict__ colj,
    float* __restrict__ evals)
{
  int b  = blockIdx.x;   // 0..63
  int mc = blockIdx.y;   // 0..31

  __shared__ float lhsL[512 * 13];  // stride 13: conflict-free
  __shared__ float sL[4][512];
  __shared__ float rh[MCH * 12];

  int tid = threadIdx.x;
  const float* src = lhs + (size_t)b * 512 * 12;
  for (int i = tid; i < 6144; i += 256) {
    int k = i / 12, t = i - k * 12;
    lhsL[k * 13 + t] = src[i];
  }
  if (tid < MCH * 12) rh[tid] = rhsS[((size_t)b * 512 + mc * MCH) * 12 + tid];
  __syncthreads();

  int wave = tid >> 6, lane = tid & 63;
  int grp = lane >> 4, lg = lane & 15;

  for (int g = 0; g < MCH / 4; ++g) {
    if (g) __syncthreads();
    for (int i = tid; i < 4 * 512; i += 256) {
      int w = i >> 9, k = i & 511;
      int m = mc * MCH + g * 4 + w;
      float p = beT[m * 512 + k];
      const float* lr = &lhsL[k * 13];
      const float* rw = &rh[(g * 4 + w) * 12];
      #pragma unroll
      for (int t = 0; t < 12; ++t) p += lr[t] * rw[t];
      sL[w][k] = 1.0f / (1.0f + __expf(-p));
    }
    __syncthreads();

    int m = mc * MCH + g * 4 + wave;
    int cnt = ccnt[m];
    if (cnt > MAXNZ) cnt = MAXNZ;
    const float* sw = sL[wave];
    for (int e = grp; e < cnt; e += 4) {
      unsigned pk = colj[m * MAXNZ + e];
      int j = pk & 0xffff, slot = (int)(pk >> 16);
      const float* vr = Ve + (size_t)j * 512;
      float part = 0.f;
      #pragma unroll
      for (int kk = 0; kk < 32; ++kk)
        part = fmaf(vr[kk * 16 + lg], sw[kk * 16 + lg], part);
      #pragma unroll
      for (int off = 8; off; off >>= 1) part += __shfl_xor(part, off, 64);
      if (lg == 0) evals[((size_t)b * 512 + j) * MAXNZ + slot] = part;
    }
  }
}

// ---------------------------------------------------------------------------
// Kernel 6: masked softmax (unchanged)
// ---------------------------------------------------------------------------
__global__ __launch_bounds__(256) void k_softmax(
    const int* __restrict__ nnz, float* __restrict__ evals)
{
  int unit = blockIdx.x * 4 + (threadIdx.x >> 6);  // b*512 + j
  int lane = threadIdx.x & 63;
  int j = unit & 511;
  int cnt = nnz[j];
  float* ev = evals + (size_t)unit * MAXNZ;
  float v0 = lane < cnt        ? ev[lane]      : -__builtin_inff();
  float v1 = (lane + 64) < cnt ? ev[lane + 64] : -__builtin_inff();
  float mx = fmaxf(v0, v1);
  #pragma unroll
  for (int off = 32; off; off >>= 1) mx = fmaxf(mx, __shfl_xor(mx, off, 64));
  float e0 = lane < cnt        ? __expf(v0 - mx) : 0.f;
  float e1 = (lane + 64) < cnt ? __expf(v1 - mx) : 0.f;
  float s = wred_sum(e0 + e1);
  float inv = 1.0f / s;
  if (lane < cnt)        ev[lane]      = e0 * inv;
  if ((lane + 64) < cnt) ev[lane + 64] = e1 * inv;
}

// ---------------------------------------------------------------------------
// Kernel 7 (v7, contiguous gather from xT): wave per (b,j).
//   Per neighbor k: its whole (t,f) block is 1536 CONTIGUOUS bytes in xT.
//   Wave gathers it with 3 dwordx2 loads (offsets 0/512/1024 B — imm-folded).
//   Lane owns 3 fixed (t, f-quad) slots: elem e = r*256 + lane*4 ->
//   t = r*4 + (lane>>4), f = (lane&15)*4. Zero cross-lane shuffles.
//   Phase B: conv (LDS, uniform-addr broadcast reads) x KT (coalesced).
// XCD swizzle: grid = 8192, sbid = (bid&7)*1024 + (bid>>3) bijective.
// ---------------------------------------------------------------------------
__global__ __launch_bounds__(256) void k_out7(
    const unsigned short* __restrict__ xT,
    const int* __restrict__ nnz, const int* __restrict__ cidx,
    const float* __restrict__ evals,
    const float* __restrict__ KT, const float* __restrict__ bias,
    float* __restrict__ out)
{
  int tid = threadIdx.x;
  int wv = tid >> 6, lane = tid & 63;
  int bid = blockIdx.x;
  int sbid = (bid & 7) * 1024 + (bid >> 3);  // bijective on [0,8192)
  int unit = sbid * 4 + wv;                  // b*512 + j
  int b = unit >> 9, j = unit & 511;

  __shared__ float convL[4][12][64];   // 12 KB
  __shared__ float valL[4][MAXNZ];     //  2 KB
  __shared__ int   idxL[4][MAXNZ];     //  2 KB

  int cnt = nnz[j];
  for (int s = lane; s < cnt; s += 64) {
    idxL[wv][s] = cidx[j * MAXNZ + s];
    valL[wv][s] = evals[(size_t)unit * MAXNZ + s];
  }
  // wave-private LDS + same-wave program order => no barrier needed here

  float4 acc0 = make_float4(0.f,0.f,0.f,0.f);
  float4 acc1 = make_float4(0.f,0.f,0.f,0.f);
  float4 acc2 = make_float4(0.f,0.f,0.f,0.f);

  const unsigned short* xbb = xT + (size_t)b * NN * (TT * FF);
  for (int s = 0; s < cnt; ++s) {
    int   k = idxL[wv][s];           // uniform LDS broadcast
    float v = valL[wv][s];
    const uint2* p = reinterpret_cast<const uint2*>(xbb + (size_t)k * (TT * FF)) + lane;
    uint2 u0 = p[0];                  // bytes [lane*8 + 0)
    uint2 u1 = p[64];                 // +512 B  (imm offset)
    uint2 u2 = p[128];                // +1024 B (imm offset)
    acc0.x = fmaf(v, bflo(u0.x), acc0.x); acc0.y = fmaf(v, bfhi(u0.x), acc0.y);
    acc0.z = fmaf(v, bflo(u0.y), acc0.z); acc0.w = fmaf(v, bfhi(u0.y), acc0.w);
    acc1.x = fmaf(v, bflo(u1.x), acc1.x); acc1.y = fmaf(v, bfhi(u1.x), acc1.y);
    acc1.z = fmaf(v, bflo(u1.y), acc1.z); acc1.w = fmaf(v, bfhi(u1.y), acc1.w);
    acc2.x = fmaf(v, bflo(u2.x), acc2.x); acc2.y = fmaf(v, bfhi(u2.x), acc2.y);
    acc2.z = fmaf(v, bflo(u2.y), acc2.z); acc2.w = fmaf(v, bfhi(u2.y), acc2.w);
  }

  // scatter: r-th acc -> t = r*4 + (lane>>4), f quad = (lane&15)*4
  int trow = lane >> 4, fq = (lane & 15) * 4;
  *(float4*)&convL[wv][0 + trow][fq] = acc0;
  *(float4*)&convL[wv][4 + trow][fq] = acc1;
  *(float4*)&convL[wv][8 + trow][fq] = acc2;

  const float4* kt4 = (const float4*)(KT + lane * 64);
  float bs = bias[lane];
  __syncthreads();  // safety; waves are independent, cost is small

  #pragma unroll
  for (int t = 0; t < 12; ++t) {
    const float4* cv = (const float4*)convL[wv][t];
    float o = bs;
    #pragma unroll
    for (int i = 0; i < 16; ++i) {
      float4 c4 = cv[i];
      float4 k4 = kt4[i];
      o += c4.x * k4.x + c4.y * k4.y + c4.z * k4.z + c4.w * k4.w;
    }
    out[((size_t)(b * TT + t) * NN + j) * UU + lane] = o;
  }
}

// ---------------------------------------------------------------------------
// Kernel 7 fallback (fp32 gather from original x) — if ws too small for xT
// ---------------------------------------------------------------------------
__global__ __launch_bounds__(256) void k_out6f(
    const float* __restrict__ x,
    const int* __restrict__ nnz, const int* __restrict__ cidx,
    const float* __restrict__ evals,
    const float* __restrict__ KT, const float* __restrict__ bias,
    float* __restrict__ out)
{
  int tid = threadIdx.x;
  int wv = tid >> 6, lane = tid & 63;
  int bid = blockIdx.x;
  int sbid = (bid & 7) * 1024 + (bid >> 3);
  int unit = sbid * 4 + wv;
  int b = unit >> 9, j = unit & 511;

  __shared__ float convL[4][12][64];
  __shared__ float valL[4][MAXNZ];
  __shared__ int   idxL[4][MAXNZ];

  int cnt = nnz[j];
  int cnt4 = (cnt + 3) & ~3;
  for (int s = lane; s < cnt; s += 64) {
    idxL[wv][s] = cidx[j * MAXNZ + s];
    valL[wv][s] = evals[(size_t)unit * MAXNZ + s];
  }
  for (int s = cnt + lane; s < cnt4; s += 64) { idxL[wv][s] = 0; valL[wv][s] = 0.f; }

  int s4 = lane >> 4, f4 = lane & 15;
  float4 acc[12];
  #pragma unroll
  for (int t = 0; t < 12; ++t) acc[t] = make_float4(0.f, 0.f, 0.f, 0.f);

  const float* xb = x + (size_t)b * TT * NN * FF;
  for (int sq = 0; sq < cnt4; sq += 4) {
    int   k = idxL[wv][sq + s4];
    float v = valL[wv][sq + s4];
    const float4* xk4 = (const float4*)(xb + (size_t)k * FF) + f4;
    #pragma unroll
    for (int t = 0; t < 12; ++t) {
      float4 xv = xk4[t * (NN * FF / 4)];
      acc[t].x = fmaf(v, xv.x, acc[t].x);
      acc[t].y = fmaf(v, xv.y, acc[t].y);
      acc[t].z = fmaf(v, xv.z, acc[t].z);
      acc[t].w = fmaf(v, xv.w, acc[t].w);
    }
  }
  #pragma unroll
  for (int t = 0; t < 12; ++t) {
    float4 a = acc[t];
    a.x += __shfl_xor(a.x, 16, 64); a.y += __shfl_xor(a.y, 16, 64);
    a.z += __shfl_xor(a.z, 16, 64); a.w += __shfl_xor(a.w, 16, 64);
    a.x += __shfl_xor(a.x, 32, 64); a.y += __shfl_xor(a.y, 32, 64);
    a.z += __shfl_xor(a.z, 32, 64); a.w += __shfl_xor(a.w, 32, 64);
    if (s4 == 0) *(float4*)&convL[wv][t][f4 * 4] = a;
  }

  const float4* kt4 = (const float4*)(KT + lane * 64);
  float bs = bias[lane];
  __syncthreads();

  #pragma unroll
  for (int t = 0; t < 12; ++t) {
    const float4* cv = (const float4*)convL[wv][t];
    float o = bs;
    #pragma unroll
    for (int i = 0; i < 16; ++i) {
      float4 c4 = cv[i];
      float4 k4 = kt4[i];
      o += c4.x * k4.x + c4.y * k4.y + c4.z * k4.z + c4.w * k4.w;
    }
    out[((size_t)(b * TT + t) * NN + j) * UU + lane] = o;
  }
}

// ---------------------------------------------------------------------------
extern "C" void kernel_launch(void* const* d_in, const int* in_sizes, int n_in,
                              void* d_out, int out_size, void* d_ws, size_t ws_size,
                              hipStream_t stream)
{
  const float* x    = (const float*)d_in[0];  // (B,T,N,F)
  const float* A    = (const float*)d_in[1];  // (N,N)
  const float* W1   = (const float*)d_in[2];  // (T,1)
  const float* W2   = (const float*)d_in[3];  // (F,T)
  const float* W3   = (const float*)d_in[4];  // (F,1)
  const float* Ve   = (const float*)d_in[5];  // (N,N)
  const float* be   = (const float*)d_in[6];  // (N,N)
  const float* K    = (const float*)d_in[7];  // (F,U)
  const float* bias = (const float*)d_in[8];  // (U,)
  float* out = (float*)d_out;

  char* ws = (char*)d_ws;
  float* lhs   = (float*)ws + OF_LHS;
  float* rhsS  = (float*)ws + OF_RHS;
  float* beT   = (float*)ws + OF_BET;
  float* evals = (float*)ws + OF_EVALS;
  int*      nnz  = (int*)(ws + OB_NNZ);
  int*      cidx = (int*)(ws + OB_CIDX);
  int*      ccnt = (int*)(ws + OB_CCNT);
  unsigned* colj = (unsigned*)(ws + OB_COLJ);
  float*    KT   = (float*)(ws + OB_KT);
  unsigned short* xT = (unsigned short*)(ws + OB_XT);

  const bool use_xt = ws_size >= OB_XT + XT_BYTES;

  hipMemsetAsync(ccnt, 0, NN * sizeof(int), stream);

  // 1. lhs / rhs (+ transposed bf16 copy of x when ws allows)
  k_lhs_rhs<<<dim3(BB * NN / 4), dim3(256), 0, stream>>>(
      x, W1, W2, W3, lhs, rhsS, use_xt ? xT : nullptr);
  // 2. transpose be (+ KT)
  k_transpose<<<dim3(NN * NN / 256 + 1), dim3(256), 0, stream>>>(be, beT, K, KT);
  // 3. row index lists
  k_build_idx<<<dim3(NN), dim3(64), 0, stream>>>(A, nnz, cidx);
  // 4. column lists
  k_build_col<<<dim3(NN), dim3(64), 0, stream>>>(nnz, cidx, ccnt, colj);
  // 5. product + sigmoid + masked E
  k_product_E<<<dim3(BB, NN / MCH), dim3(256), 0, stream>>>(lhs, rhsS, beT, Ve, ccnt, colj, evals);
  // 6. softmax over slots
  k_softmax<<<dim3(BB * NN / 4), dim3(256), 0, stream>>>(nnz, evals);
  // 7. sparse conv (contiguous 1536B-per-neighbor gather) + output GEMM
  if (use_xt)
    k_out7<<<dim3(BB * NN / 4), dim3(256), 0, stream>>>(xT, nnz, cidx, evals, KT, bias, out);
  else
    k_out6f<<<dim3(BB * NN / 4), dim3(256), 0, stream>>>(x, nnz, cidx, evals, KT, bias, out);
}

// Round 9
// 283.465 us; speedup vs baseline: 9.1672x; 9.0797x over previous
//
#include <hip/hip_runtime.h>
#include <hip/hip_bf16.h>
#include <cstdint>

// Problem constants
constexpr int BB = 64;    // batch
constexpr int TT = 12;    // time
constexpr int NN = 512;   // nodes
constexpr int FF = 64;    // features
constexpr int UU = 64;    // units
constexpr int MAXNZ = 128;
constexpr int MCH = 16;   // m-columns per k_product_E block

// ---------------------------------------------------------------------------
// Workspace layout (bytes):
//   floats: lhs 0 / rhs 393216f / beT 786432f / evals 1048576f
//   ints:   nnz 20971520 / cidx 20973568 / ccnt 21235712 / colj 21237760
//   xb16 (B,T,N,F) bf16 : 21516288, 50331648 B  (same layout as x)
// ---------------------------------------------------------------------------
constexpr size_t OF_LHS   = 0;
constexpr size_t OF_RHS   = 393216;
constexpr size_t OF_BET   = 786432;
constexpr size_t OF_EVALS = 1048576;
constexpr size_t OB_NNZ   = 20971520;
constexpr size_t OB_CIDX  = 20973568;
constexpr size_t OB_CCNT  = 21235712;
constexpr size_t OB_COLJ  = 21237760;
constexpr size_t OB_XB16  = 21516288;
constexpr size_t XB16_BYTES = (size_t)BB * TT * NN * FF * 2;  // 50331648

__device__ __forceinline__ float wred_sum(float v) {
  #pragma unroll
  for (int off = 32; off; off >>= 1) v += __shfl_xor(v, off, 64);
  return v;
}

// ---------------------------------------------------------------------------
// Kernel 1: lhs/rhs reductions; also writes xb16 (bf16 copy of x, SAME
// (B,T,N,F) layout) — xv[12] is already register-resident here.
// ---------------------------------------------------------------------------
__global__ __launch_bounds__(256) void k_lhs_rhs(
    const float* __restrict__ x, const float* __restrict__ W1,
    const float* __restrict__ W2, const float* __restrict__ W3,
    float* __restrict__ lhs, float* __restrict__ rhsS,
    unsigned short* __restrict__ xb16)   // may be null
{
  int unit = blockIdx.x * 4 + (threadIdx.x >> 6);   // b*512 + n
  int lane = threadIdx.x & 63;
  int b = unit >> 9, n = unit & 511;

  const float* xb = x + ((size_t)b * TT * NN + n) * FF + lane;
  float xv[12];
  #pragma unroll
  for (int t = 0; t < 12; ++t) xv[t] = xb[(size_t)t * NN * FF];

  if (xb16) {
    unsigned short* xo = xb16 + ((size_t)b * TT * NN + n) * FF + lane;
    #pragma unroll
    for (int t = 0; t < 12; ++t) {
      __hip_bfloat16 h = __float2bfloat16(xv[t]);   // RTNE
      xo[(size_t)t * NN * FF] = *reinterpret_cast<unsigned short*>(&h);
    }
  }

  float r1 = 0.f;
  #pragma unroll
  for (int t = 0; t < 12; ++t) r1 += xv[t] * W1[t];

  float w3 = W3[lane];

  float myl = 0.f, myr = 0.f;
  #pragma unroll
  for (int t = 0; t < 12; ++t) {
    float a = r1 * W2[lane * 12 + t];
    float c = xv[t] * w3;
    a = wred_sum(a);
    c = wred_sum(c);
    if (lane == t) { myl = a; myr = c; }
  }
  if (lane < 12) {
    lhs[(size_t)unit * 12 + lane]  = myl;
    rhsS[(size_t)unit * 12 + lane] = myr;
  }
}

// ---------------------------------------------------------------------------
// Kernel 2: beT[m,k] = be[k,m]
// ---------------------------------------------------------------------------
__global__ __launch_bounds__(256) void k_transpose(
    const float* __restrict__ be, float* __restrict__ beT)
{
  int i = blockIdx.x * 256 + threadIdx.x;  // 262144 total
  int k = i >> 9, m = i & 511;
  beT[m * 512 + k] = be[i];
}

// ---------------------------------------------------------------------------
// Kernel 3: row-wise compaction of mask A (deterministic, ordered by m)
// ---------------------------------------------------------------------------
__global__ void k_build_idx(const float* __restrict__ A,
                            int* __restrict__ nnz, int* __restrict__ cidx)
{
  int j = blockIdx.x;
  int lane = threadIdx.x;  // 64 threads
  unsigned long long lt = (1ull << lane) - 1ull;
  int base = 0;
  for (int c = 0; c < 8; ++c) {
    int m = c * 64 + lane;
    bool p = A[(size_t)j * 512 + m] > 0.5f;
    unsigned long long mask = __ballot(p);
    int pos = base + __popcll(mask & lt);
    if (p && pos < MAXNZ) cidx[j * MAXNZ + pos] = m;
    base += __popcll(mask);
  }
  if (lane == 0) nnz[j] = base > MAXNZ ? MAXNZ : base;
}

// ---------------------------------------------------------------------------
// Kernel 4: column lists
// ---------------------------------------------------------------------------
__global__ void k_build_col(const int* __restrict__ nnz, const int* __restrict__ cidx,
                            int* __restrict__ ccnt, unsigned* __restrict__ colj)
{
  int j = blockIdx.x;
  int lane = threadIdx.x;
  int cnt = nnz[j];
  for (int s = lane; s < cnt; s += 64) {
    int m = cidx[j * MAXNZ + s];
    int pos = atomicAdd(&ccnt[m], 1);
    if (pos < MAXNZ) colj[m * MAXNZ + pos] = (unsigned)j | ((unsigned)s << 16);
  }
}

// ---------------------------------------------------------------------------
// Kernel 5 (v2): unchanged (16 columns/block, 16-lane entry groups)
// ---------------------------------------------------------------------------
__global__ __launch_bounds__(256) void k_product_E(
    const float* __restrict__ lhs, const float* __restrict__ rhsS,
    const float* __restrict__ beT, const float* __restrict__ Ve,
    const int* __restrict__ ccnt, const unsigned* __restrict__ colj,
    float* __restrict__ evals)
{
  int b  = blockIdx.x;   // 0..63
  int mc = blockIdx.y;   // 0..31

  __shared__ float lhsL[512 * 13];  // stride 13: conflict-free
  __shared__ float sL[4][512];
  __shared__ float rh[MCH * 12];

  int tid = threadIdx.x;
  const float* src = lhs + (size_t)b * 512 * 12;
  for (int i = tid; i < 6144; i += 256) {
    int k = i / 12, t = i - k * 12;
    lhsL[k * 13 + t] = src[i];
  }
  if (tid < MCH * 12) rh[tid] = rhsS[((size_t)b * 512 + mc * MCH) * 12 + tid];
  __syncthreads();

  int wave = tid >> 6, lane = tid & 63;
  int grp = lane >> 4, lg = lane & 15;

  for (int g = 0; g < MCH / 4; ++g) {
    if (g) __syncthreads();
    for (int i = tid; i < 4 * 512; i += 256) {
      int w = i >> 9, k = i & 511;
      int m = mc * MCH + g * 4 + w;
      float p = beT[m * 512 + k];
      const float* lr = &lhsL[k * 13];
      const float* rw = &rh[(g * 4 + w) * 12];
      #pragma unroll
      for (int t = 0; t < 12; ++t) p += lr[t] * rw[t];
      sL[w][k] = 1.0f / (1.0f + __expf(-p));
    }
    __syncthreads();

    int m = mc * MCH + g * 4 + wave;
    int cnt = ccnt[m];
    if (cnt > MAXNZ) cnt = MAXNZ;
    const float* sw = sL[wave];
    for (int e = grp; e < cnt; e += 4) {
      unsigned pk = colj[m * MAXNZ + e];
      int j = pk & 0xffff, slot = (int)(pk >> 16);
      const float* vr = Ve + (size_t)j * 512;
      float part = 0.f;
      #pragma unroll
      for (int kk = 0; kk < 32; ++kk)
        part = fmaf(vr[kk * 16 + lg], sw[kk * 16 + lg], part);
      #pragma unroll
      for (int off = 8; off; off >>= 1) part += __shfl_xor(part, off, 64);
      if (lg == 0) evals[((size_t)b * 512 + j) * MAXNZ + slot] = part;
    }
  }
}

// ---------------------------------------------------------------------------
// Kernel 6: masked softmax (unchanged)
// ---------------------------------------------------------------------------
__global__ __launch_bounds__(256) void k_softmax(
    const int* __restrict__ nnz, float* __restrict__ evals)
{
  int unit = blockIdx.x * 4 + (threadIdx.x >> 6);  // b*512 + j
  int lane = threadIdx.x & 63;
  int j = unit & 511;
  int cnt = nnz[j];
  float* ev = evals + (size_t)unit * MAXNZ;
  float v0 = lane < cnt        ? ev[lane]      : -__builtin_inff();
  float v1 = (lane + 64) < cnt ? ev[lane + 64] : -__builtin_inff();
  float mx = fmaxf(v0, v1);
  #pragma unroll
  for (int off = 32; off; off >>= 1) mx = fmaxf(mx, __shfl_xor(mx, off, 64));
  float e0 = lane < cnt        ? __expf(v0 - mx) : 0.f;
  float e1 = (lane + 64) < cnt ? __expf(v1 - mx) : 0.f;
  float s = wred_sum(e0 + e1);
  float inv = 1.0f / s;
  if (lane < cnt)        ev[lane]      = e0 * inv;
  if ((lane + 64) < cnt) ev[lane + 64] = e1 * inv;
}

// ---------------------------------------------------------------------------
// Kernel 7 (v8): wave per (b,j). bf16 phase A + EXACT v3 phase B.
//   Phase A: half = lane>>5 (t 0..5 / 6..11), fl = lane&31 (f = 2fl, 2fl+1).
//   Per neighbor: 6 uint loads (2 bf16 each), 12 unpack (__uint_as_float,
//   no address-of-local), 12 FMA, zero shuffles. VMEM count and L2 bytes
//   both HALF of v3. Each (t,f) owned by one lane -> direct conv write.
//   Phase B: unchanged from v3 (kc from K[f*64+lane]; measured VGPR 48,
//   occ 50%, the 150 us config). v6/v7 died because KT-form phase B made
//   the compiler hoist 64 K values -> VGPR 140 -> occ 12% -> latency-naked.
// XCD swizzle: grid = 8192, sbid = (bid&7)*1024 + (bid>>3) bijective.
// ---------------------------------------------------------------------------
__global__ __launch_bounds__(256) void k_out8(
    const unsigned short* __restrict__ xb16,
    const int* __restrict__ nnz, const int* __restrict__ cidx,
    const float* __restrict__ evals,
    const float* __restrict__ K, const float* __restrict__ bias,
    float* __restrict__ out)
{
  int tid = threadIdx.x;
  int wv = tid >> 6, lane = tid & 63;
  int bid = blockIdx.x;
  int sbid = (bid & 7) * 1024 + (bid >> 3);  // bijective on [0,8192)
  int unit = sbid * 4 + wv;                  // b*512 + j
  int b = unit >> 9, j = unit & 511;

  __shared__ float convL[4][12][64];   // 12 KB
  __shared__ float valL[4][MAXNZ];     //  2 KB
  __shared__ int   idxL[4][MAXNZ];     //  2 KB

  int cnt = nnz[j];
  for (int s = lane; s < cnt; s += 64) {
    idxL[wv][s] = cidx[j * MAXNZ + s];
    valL[wv][s] = evals[(size_t)unit * MAXNZ + s];
  }
  // wave-private LDS + same-wave program order => no barrier needed here

  int half = lane >> 5;   // 0: t=0..5, 1: t=6..11
  int fl   = lane & 31;   // features 2*fl, 2*fl+1

  float2 acc[6];
  #pragma unroll
  for (int i = 0; i < 6; ++i) acc[i] = make_float2(0.f, 0.f);

  // base for this lane's t-half
  const unsigned short* xh = xb16 + (size_t)(b * TT + half * 6) * NN * FF;
  for (int s = 0; s < cnt; ++s) {
    int   k = idxL[wv][s];           // uniform LDS broadcast
    float v = valL[wv][s];
    const unsigned* xk = reinterpret_cast<const unsigned*>(xh + (size_t)k * FF) + fl;
    #pragma unroll
    for (int i = 0; i < 6; ++i) {
      unsigned u = xk[(size_t)i * (NN * FF / 2)];
      acc[i].x = fmaf(v, __uint_as_float(u << 16),         acc[i].x);
      acc[i].y = fmaf(v, __uint_as_float(u & 0xFFFF0000u), acc[i].y);
    }
  }

  #pragma unroll
  for (int i = 0; i < 6; ++i)
    *(float2*)&convL[wv][half * 6 + i][fl * 2] = acc[i];   // 2-way bank alias: free

  // EXACT v3 phase B
  float kc[64];
  #pragma unroll
  for (int f = 0; f < 64; ++f) kc[f] = K[f * 64 + lane];
  float bs = bias[lane];
  __syncthreads();  // conv tiles visible across lanes

  #pragma unroll
  for (int t = 0; t < 12; ++t) {
    const float4* cv = (const float4*)convL[wv][t];
    float o = bs;
    #pragma unroll
    for (int i = 0; i < 16; ++i) {
      float4 c4 = cv[i];
      o += c4.x * kc[4*i] + c4.y * kc[4*i+1] + c4.z * kc[4*i+2] + c4.w * kc[4*i+3];
    }
    out[((size_t)(b * TT + t) * NN + j) * UU + lane] = o;
  }
}

// ---------------------------------------------------------------------------
// Kernel 7 fallback (EXACT v3: fp32 scalar gather + kc phase B) — if ws small
// ---------------------------------------------------------------------------
__global__ __launch_bounds__(256) void k_out3f(
    const float* __restrict__ x,
    const int* __restrict__ nnz, const int* __restrict__ cidx,
    const float* __restrict__ evals,
    const float* __restrict__ K, const float* __restrict__ bias,
    float* __restrict__ out)
{
  int wv = threadIdx.x >> 6, lane = threadIdx.x & 63;
  int bid = blockIdx.x;
  int sbid = (bid & 7) * 1024 + (bid >> 3);
  int unit = sbid * 4 + wv;
  int b = unit >> 9, j = unit & 511;

  __shared__ float convL[4][12][64];
  __shared__ float valL[4][MAXNZ];
  __shared__ int   idxL[4][MAXNZ];

  int cnt = nnz[j];
  for (int s = lane; s < cnt; s += 64) {
    idxL[wv][s] = cidx[j * MAXNZ + s];
    valL[wv][s] = evals[(size_t)unit * MAXNZ + s];
  }

  float acc[12];
  #pragma unroll
  for (int t = 0; t < 12; ++t) acc[t] = 0.f;

  const float* xb = x + (size_t)b * TT * NN * FF + lane;
  for (int s = 0; s < cnt; ++s) {
    float v = valL[wv][s];
    const float* xk = xb + (size_t)idxL[wv][s] * FF;
    #pragma unroll
    for (int t = 0; t < 12; ++t)
      acc[t] = fmaf(v, xk[(size_t)t * NN * FF], acc[t]);
  }
  #pragma unroll
  for (int t = 0; t < 12; ++t) convL[wv][t][lane] = acc[t];

  float kc[64];
  #pragma unroll
  for (int f = 0; f < 64; ++f) kc[f] = K[f * 64 + lane];
  float bs = bias[lane];
  __syncthreads();

  #pragma unroll
  for (int t = 0; t < 12; ++t) {
    const float4* cv = (const float4*)convL[wv][t];
    float o = bs;
    #pragma unroll
    for (int i = 0; i < 16; ++i) {
      float4 c4 = cv[i];
      o += c4.x * kc[4*i] + c4.y * kc[4*i+1] + c4.z * kc[4*i+2] + c4.w * kc[4*i+3];
    }
    out[((size_t)(b * TT + t) * NN + j) * UU + lane] = o;
  }
}

// ---------------------------------------------------------------------------
extern "C" void kernel_launch(void* const* d_in, const int* in_sizes, int n_in,
                              void* d_out, int out_size, void* d_ws, size_t ws_size,
                              hipStream_t stream)
{
  const float* x    = (const float*)d_in[0];  // (B,T,N,F)
  const float* A    = (const float*)d_in[1];  // (N,N)
  const float* W1   = (const float*)d_in[2];  // (T,1)
  const float* W2   = (const float*)d_in[3];  // (F,T)
  const float* W3   = (const float*)d_in[4];  // (F,1)
  const float* Ve   = (const float*)d_in[5];  // (N,N)
  const float* be   = (const float*)d_in[6];  // (N,N)
  const float* K    = (const float*)d_in[7];  // (F,U)
  const float* bias = (const float*)d_in[8];  // (U,)
  float* out = (float*)d_out;

  char* ws = (char*)d_ws;
  float* lhs   = (float*)ws + OF_LHS;
  float* rhsS  = (float*)ws + OF_RHS;
  float* beT   = (float*)ws + OF_BET;
  float* evals = (float*)ws + OF_EVALS;
  int*      nnz  = (int*)(ws + OB_NNZ);
  int*      cidx = (int*)(ws + OB_CIDX);
  int*      ccnt = (int*)(ws + OB_CCNT);
  unsigned* colj = (unsigned*)(ws + OB_COLJ);
  unsigned short* xb16 = (unsigned short*)(ws + OB_XB16);

  const bool use_bf16 = ws_size >= OB_XB16 + XB16_BYTES;

  hipMemsetAsync(ccnt, 0, NN * sizeof(int), stream);

  // 1. lhs / rhs (+ bf16 copy of x, same layout)
  k_lhs_rhs<<<dim3(BB * NN / 4), dim3(256), 0, stream>>>(
      x, W1, W2, W3, lhs, rhsS, use_bf16 ? xb16 : nullptr);
  // 2. transpose be
  k_transpose<<<dim3(NN * NN / 256), dim3(256), 0, stream>>>(be, beT);
  // 3. row index lists
  k_build_idx<<<dim3(NN), dim3(64), 0, stream>>>(A, nnz, cidx);
  // 4. column lists
  k_build_col<<<dim3(NN), dim3(64), 0, stream>>>(nnz, cidx, ccnt, colj);
  // 5. product + sigmoid + masked E
  k_product_E<<<dim3(BB, NN / MCH), dim3(256), 0, stream>>>(lhs, rhsS, beT, Ve, ccnt, colj, evals);
  // 6. softmax over slots
  k_softmax<<<dim3(BB * NN / 4), dim3(256), 0, stream>>>(nnz, evals);
  // 7. sparse conv (bf16, half bytes/VMEM) + v3 output GEMM
  if (use_bf16)
    k_out8<<<dim3(BB * NN / 4), dim3(256), 0, stream>>>(xb16, nnz, cidx, evals, K, bias, out);
  else
    k_out3f<<<dim3(BB * NN / 4), dim3(256), 0, stream>>>(x, nnz, cidx, evals, K, bias, out);
}

// Round 10
// 271.612 us; speedup vs baseline: 9.5672x; 1.0436x over previous
//
#include <hip/hip_runtime.h>
#include <hip/hip_bf16.h>
#include <cstdint>

// Problem constants
constexpr int BB = 64;    // batch
constexpr int TT = 12;    // time
constexpr int NN = 512;   // nodes
constexpr int FF = 64;    // features
constexpr int UU = 64;    // units
constexpr int MAXNZ = 128;
constexpr int MCH = 16;   // m-columns per k_product_E block

// ---------------------------------------------------------------------------
// Workspace layout (bytes):
//   floats: lhs 0 / rhs 393216f / beT 786432f / evals 1048576f
//   ints:   nnz 20971520 / cidx 20973568 / ccnt 21235712 / colj 21237760
//   xT (B,N,T,F) bf16 : 21516288, 50331648 B  (transposed bf16 copy of x)
// ---------------------------------------------------------------------------
constexpr size_t OF_LHS   = 0;
constexpr size_t OF_RHS   = 393216;
constexpr size_t OF_BET   = 786432;
constexpr size_t OF_EVALS = 1048576;
constexpr size_t OB_NNZ   = 20971520;
constexpr size_t OB_CIDX  = 20973568;
constexpr size_t OB_CCNT  = 21235712;
constexpr size_t OB_COLJ  = 21237760;
constexpr size_t OB_XT    = 21516288;
constexpr size_t XT_BYTES = (size_t)BB * NN * TT * FF * 2;  // 50331648

__device__ __forceinline__ float wred_sum(float v) {
  #pragma unroll
  for (int off = 32; off; off >>= 1) v += __shfl_xor(v, off, 64);
  return v;
}

__device__ __forceinline__ float bflo(unsigned u) {
  return __uint_as_float(u << 16);
}
__device__ __forceinline__ float bfhi(unsigned u) {
  return __uint_as_float(u & 0xFFFF0000u);
}

// ---------------------------------------------------------------------------
// Kernel 1: lhs/rhs reductions; also writes xT[b][n][t][f] (bf16 transposed
// copy of x) — xv[12] is already register-resident here.
// ---------------------------------------------------------------------------
__global__ __launch_bounds__(256) void k_lhs_rhs(
    const float* __restrict__ x, const float* __restrict__ W1,
    const float* __restrict__ W2, const float* __restrict__ W3,
    float* __restrict__ lhs, float* __restrict__ rhsS,
    unsigned short* __restrict__ xT)   // may be null
{
  int unit = blockIdx.x * 4 + (threadIdx.x >> 6);   // b*512 + n
  int lane = threadIdx.x & 63;
  int b = unit >> 9, n = unit & 511;

  const float* xb = x + ((size_t)b * TT * NN + n) * FF + lane;
  float xv[12];
  #pragma unroll
  for (int t = 0; t < 12; ++t) xv[t] = xb[(size_t)t * NN * FF];

  if (xT) {
    // xT[b][n][t][f]: per t, 64 lanes write 128 contiguous bytes
    unsigned short* xo = xT + (size_t)unit * (TT * FF) + lane;
    #pragma unroll
    for (int t = 0; t < 12; ++t) {
      __hip_bfloat16 h = __float2bfloat16(xv[t]);   // RTNE
      xo[t * FF] = *reinterpret_cast<unsigned short*>(&h);
    }
  }

  float r1 = 0.f;
  #pragma unroll
  for (int t = 0; t < 12; ++t) r1 += xv[t] * W1[t];

  float w3 = W3[lane];

  float myl = 0.f, myr = 0.f;
  #pragma unroll
  for (int t = 0; t < 12; ++t) {
    float a = r1 * W2[lane * 12 + t];
    float c = xv[t] * w3;
    a = wred_sum(a);
    c = wred_sum(c);
    if (lane == t) { myl = a; myr = c; }
  }
  if (lane < 12) {
    lhs[(size_t)unit * 12 + lane]  = myl;
    rhsS[(size_t)unit * 12 + lane] = myr;
  }
}

// ---------------------------------------------------------------------------
// Kernel 2: beT[m,k] = be[k,m]
// ---------------------------------------------------------------------------
__global__ __launch_bounds__(256) void k_transpose(
    const float* __restrict__ be, float* __restrict__ beT)
{
  int i = blockIdx.x * 256 + threadIdx.x;  // 262144 total
  int k = i >> 9, m = i & 511;
  beT[m * 512 + k] = be[i];
}

// ---------------------------------------------------------------------------
// Kernel 3: row-wise compaction of mask A (deterministic, ordered by m)
// ---------------------------------------------------------------------------
__global__ void k_build_idx(const float* __restrict__ A,
                            int* __restrict__ nnz, int* __restrict__ cidx)
{
  int j = blockIdx.x;
  int lane = threadIdx.x;  // 64 threads
  unsigned long long lt = (1ull << lane) - 1ull;
  int base = 0;
  for (int c = 0; c < 8; ++c) {
    int m = c * 64 + lane;
    bool p = A[(size_t)j * 512 + m] > 0.5f;
    unsigned long long mask = __ballot(p);
    int pos = base + __popcll(mask & lt);
    if (p && pos < MAXNZ) cidx[j * MAXNZ + pos] = m;
    base += __popcll(mask);
  }
  if (lane == 0) nnz[j] = base > MAXNZ ? MAXNZ : base;
}

// ---------------------------------------------------------------------------
// Kernel 4: column lists
// ---------------------------------------------------------------------------
__global__ void k_build_col(const int* __restrict__ nnz, const int* __restrict__ cidx,
                            int* __restrict__ ccnt, unsigned* __restrict__ colj)
{
  int j = blockIdx.x;
  int lane = threadIdx.x;
  int cnt = nnz[j];
  for (int s = lane; s < cnt; s += 64) {
    int m = cidx[j * MAXNZ + s];
    int pos = atomicAdd(&ccnt[m], 1);
    if (pos < MAXNZ) colj[m * MAXNZ + pos] = (unsigned)j | ((unsigned)s << 16);
  }
}

// ---------------------------------------------------------------------------
// Kernel 5 (v2): unchanged (16 columns/block, 16-lane entry groups)
// ---------------------------------------------------------------------------
__global__ __launch_bounds__(256) void k_product_E(
    const float* __restrict__ lhs, const float* __restrict__ rhsS,
    const float* __restrict__ beT, const float* __restrict__ Ve,
    const int* __restrict__ ccnt, const unsigned* __restrict__ colj,
    float* __restrict__ evals)
{
  int b  = blockIdx.x;   // 0..63
  int mc = blockIdx.y;   // 0..31

  __shared__ float lhsL[512 * 13];  // stride 13: conflict-free
  __shared__ float sL[4][512];
  __shared__ float rh[MCH * 12];

  int tid = threadIdx.x;
  const float* src = lhs + (size_t)b * 512 * 12;
  for (int i = tid; i < 6144; i += 256) {
    int k = i / 12, t = i - k * 12;
    lhsL[k * 13 + t] = src[i];
  }
  if (tid < MCH * 12) rh[tid] = rhsS[((size_t)b * 512 + mc * MCH) * 12 + tid];
  __syncthreads();

  int wave = tid >> 6, lane = tid & 63;
  int grp = lane >> 4, lg = lane & 15;

  for (int g = 0; g < MCH / 4; ++g) {
    if (g) __syncthreads();
    for (int i = tid; i < 4 * 512; i += 256) {
      int w = i >> 9, k = i & 511;
      int m = mc * MCH + g * 4 + w;
      float p = beT[m * 512 + k];
      const float* lr = &lhsL[k * 13];
      const float* rw = &rh[(g * 4 + w) * 12];
      #pragma unroll
      for (int t = 0; t < 12; ++t) p += lr[t] * rw[t];
      sL[w][k] = 1.0f / (1.0f + __expf(-p));
    }
    __syncthreads();

    int m = mc * MCH + g * 4 + wave;
    int cnt = ccnt[m];
    if (cnt > MAXNZ) cnt = MAXNZ;
    const float* sw = sL[wave];
    for (int e = grp; e < cnt; e += 4) {
      unsigned pk = colj[m * MAXNZ + e];
      int j = pk & 0xffff, slot = (int)(pk >> 16);
      const float* vr = Ve + (size_t)j * 512;
      float part = 0.f;
      #pragma unroll
      for (int kk = 0; kk < 32; ++kk)
        part = fmaf(vr[kk * 16 + lg], sw[kk * 16 + lg], part);
      #pragma unroll
      for (int off = 8; off; off >>= 1) part += __shfl_xor(part, off, 64);
      if (lg == 0) evals[((size_t)b * 512 + j) * MAXNZ + slot] = part;
    }
  }
}

// ---------------------------------------------------------------------------
// Kernel 6: masked softmax (unchanged)
// ---------------------------------------------------------------------------
__global__ __launch_bounds__(256) void k_softmax(
    const int* __restrict__ nnz, float* __restrict__ evals)
{
  int unit = blockIdx.x * 4 + (threadIdx.x >> 6);  // b*512 + j
  int lane = threadIdx.x & 63;
  int j = unit & 511;
  int cnt = nnz[j];
  float* ev = evals + (size_t)unit * MAXNZ;
  float v0 = lane < cnt        ? ev[lane]      : -__builtin_inff();
  float v1 = (lane + 64) < cnt ? ev[lane + 64] : -__builtin_inff();
  float mx = fmaxf(v0, v1);
  #pragma unroll
  for (int off = 32; off; off >>= 1) mx = fmaxf(mx, __shfl_xor(mx, off, 64));
  float e0 = lane < cnt        ? __expf(v0 - mx) : 0.f;
  float e1 = (lane + 64) < cnt ? __expf(v1 - mx) : 0.f;
  float s = wred_sum(e0 + e1);
  float inv = 1.0f / s;
  if (lane < cnt)        ev[lane]      = e0 * inv;
  if ((lane + 64) < cnt) ev[lane + 64] = e1 * inv;
}

// ---------------------------------------------------------------------------
// Kernel 7 (v9): wave per (b,j). xT-layout bf16 gather + EXACT v8 phase B.
//   Phase A: neighbor row = 1536 contiguous bytes in xT. Lane reads 6 uints
//   at byte offsets lane*4 + {0,256,512,768,1024,1280} — ALL imm-foldable,
//   so addressing = 1 mul + 1 add64 per neighbor (v8 needed 6 add64 pairs at
//   64KB strides). uint w = i*64+lane -> elements 2w,2w+1:
//   t = 2i + (lane>>5), f = 2*(lane&31). Zero shuffles.
//   2-neighbor unroll: 12 loads in flight (2x MLP) to cover L2 latency.
//   Phase B: exact v8/v3 kc form (VGPR 44, occ 49% proven).
// XCD swizzle: grid = 8192, sbid = (bid&7)*1024 + (bid>>3) bijective.
// ---------------------------------------------------------------------------
__global__ __launch_bounds__(256) void k_out9(
    const unsigned short* __restrict__ xT,
    const int* __restrict__ nnz, const int* __restrict__ cidx,
    const float* __restrict__ evals,
    const float* __restrict__ K, const float* __restrict__ bias,
    float* __restrict__ out)
{
  int tid = threadIdx.x;
  int wv = tid >> 6, lane = tid & 63;
  int bid = blockIdx.x;
  int sbid = (bid & 7) * 1024 + (bid >> 3);  // bijective on [0,8192)
  int unit = sbid * 4 + wv;                  // b*512 + j
  int b = unit >> 9, j = unit & 511;

  __shared__ float convL[4][12][64];   // 12 KB
  __shared__ float valL[4][MAXNZ];     //  2 KB
  __shared__ int   idxL[4][MAXNZ];     //  2 KB

  int cnt = nnz[j];
  for (int s = lane; s < cnt; s += 64) {
    idxL[wv][s] = cidx[j * MAXNZ + s];
    valL[wv][s] = evals[(size_t)unit * MAXNZ + s];
  }
  // wave-private LDS + same-wave program order => no barrier needed here

  float2 acc[6];
  #pragma unroll
  for (int i = 0; i < 6; ++i) acc[i] = make_float2(0.f, 0.f);

  const unsigned* xb = reinterpret_cast<const unsigned*>(
      xT + (size_t)b * NN * (TT * FF));   // b-base, uint units (384/row)

  int s = 0;
  for (; s + 1 < cnt; s += 2) {
    int   k0 = idxL[wv][s],     k1 = idxL[wv][s + 1];
    float v0 = valL[wv][s],     v1 = valL[wv][s + 1];
    const unsigned* p0 = xb + k0 * 384 + lane;
    const unsigned* p1 = xb + k1 * 384 + lane;
    unsigned a0 = p0[0],   a1 = p0[64],  a2 = p0[128],
             a3 = p0[192], a4 = p0[256], a5 = p0[320];
    unsigned c0 = p1[0],   c1 = p1[64],  c2 = p1[128],
             c3 = p1[192], c4 = p1[256], c5 = p1[320];
    acc[0].x = fmaf(v0, bflo(a0), acc[0].x); acc[0].y = fmaf(v0, bfhi(a0), acc[0].y);
    acc[1].x = fmaf(v0, bflo(a1), acc[1].x); acc[1].y = fmaf(v0, bfhi(a1), acc[1].y);
    acc[2].x = fmaf(v0, bflo(a2), acc[2].x); acc[2].y = fmaf(v0, bfhi(a2), acc[2].y);
    acc[3].x = fmaf(v0, bflo(a3), acc[3].x); acc[3].y = fmaf(v0, bfhi(a3), acc[3].y);
    acc[4].x = fmaf(v0, bflo(a4), acc[4].x); acc[4].y = fmaf(v0, bfhi(a4), acc[4].y);
    acc[5].x = fmaf(v0, bflo(a5), acc[5].x); acc[5].y = fmaf(v0, bfhi(a5), acc[5].y);
    acc[0].x = fmaf(v1, bflo(c0), acc[0].x); acc[0].y = fmaf(v1, bfhi(c0), acc[0].y);
    acc[1].x = fmaf(v1, bflo(c1), acc[1].x); acc[1].y = fmaf(v1, bfhi(c1), acc[1].y);
    acc[2].x = fmaf(v1, bflo(c2), acc[2].x); acc[2].y = fmaf(v1, bfhi(c2), acc[2].y);
    acc[3].x = fmaf(v1, bflo(c3), acc[3].x); acc[3].y = fmaf(v1, bfhi(c3), acc[3].y);
    acc[4].x = fmaf(v1, bflo(c4), acc[4].x); acc[4].y = fmaf(v1, bfhi(c4), acc[4].y);
    acc[5].x = fmaf(v1, bflo(c5), acc[5].x); acc[5].y = fmaf(v1, bfhi(c5), acc[5].y);
  }
  if (s < cnt) {  // odd tail
    int   k0 = idxL[wv][s];
    float v0 = valL[wv][s];
    const unsigned* p0 = xb + k0 * 384 + lane;
    unsigned a0 = p0[0],   a1 = p0[64],  a2 = p0[128],
             a3 = p0[192], a4 = p0[256], a5 = p0[320];
    acc[0].x = fmaf(v0, bflo(a0), acc[0].x); acc[0].y = fmaf(v0, bfhi(a0), acc[0].y);
    acc[1].x = fmaf(v0, bflo(a1), acc[1].x); acc[1].y = fmaf(v0, bfhi(a1), acc[1].y);
    acc[2].x = fmaf(v0, bflo(a2), acc[2].x); acc[2].y = fmaf(v0, bfhi(a2), acc[2].y);
    acc[3].x = fmaf(v0, bflo(a3), acc[3].x); acc[3].y = fmaf(v0, bfhi(a3), acc[3].y);
    acc[4].x = fmaf(v0, bflo(a4), acc[4].x); acc[4].y = fmaf(v0, bfhi(a4), acc[4].y);
    acc[5].x = fmaf(v0, bflo(a5), acc[5].x); acc[5].y = fmaf(v0, bfhi(a5), acc[5].y);
  }

  // acc[i] -> t = 2i + (lane>>5), f = 2*(lane&31)
  int half = lane >> 5, fl = lane & 31;
  #pragma unroll
  for (int i = 0; i < 6; ++i)
    *(float2*)&convL[wv][2 * i + half][fl * 2] = acc[i];  // 2-way alias: free

  // EXACT v8 phase B
  float kc[64];
  #pragma unroll
  for (int f = 0; f < 64; ++f) kc[f] = K[f * 64 + lane];
  float bs = bias[lane];
  __syncthreads();  // conv tiles visible across lanes

  #pragma unroll
  for (int t = 0; t < 12; ++t) {
    const float4* cv = (const float4*)convL[wv][t];
    float o = bs;
    #pragma unroll
    for (int i = 0; i < 16; ++i) {
      float4 c4 = cv[i];
      o += c4.x * kc[4*i] + c4.y * kc[4*i+1] + c4.z * kc[4*i+2] + c4.w * kc[4*i+3];
    }
    out[((size_t)(b * TT + t) * NN + j) * UU + lane] = o;
  }
}

// ---------------------------------------------------------------------------
// Kernel 7 fallback (EXACT v3: fp32 scalar gather + kc phase B) — if ws small
// ---------------------------------------------------------------------------
__global__ __launch_bounds__(256) void k_out3f(
    const float* __restrict__ x,
    const int* __restrict__ nnz, const int* __restrict__ cidx,
    const float* __restrict__ evals,
    const float* __restrict__ K, const float* __restrict__ bias,
    float* __restrict__ out)
{
  int wv = threadIdx.x >> 6, lane = threadIdx.x & 63;
  int bid = blockIdx.x;
  int sbid = (bid & 7) * 1024 + (bid >> 3);
  int unit = sbid * 4 + wv;
  int b = unit >> 9, j = unit & 511;

  __shared__ float convL[4][12][64];
  __shared__ float valL[4][MAXNZ];
  __shared__ int   idxL[4][MAXNZ];

  int cnt = nnz[j];
  for (int s = lane; s < cnt; s += 64) {
    idxL[wv][s] = cidx[j * MAXNZ + s];
    valL[wv][s] = evals[(size_t)unit * MAXNZ + s];
  }

  float acc[12];
  #pragma unroll
  for (int t = 0; t < 12; ++t) acc[t] = 0.f;

  const float* xb = x + (size_t)b * TT * NN * FF + lane;
  for (int s = 0; s < cnt; ++s) {
    float v = valL[wv][s];
    const float* xk = xb + (size_t)idxL[wv][s] * FF;
    #pragma unroll
    for (int t = 0; t < 12; ++t)
      acc[t] = fmaf(v, xk[(size_t)t * NN * FF], acc[t]);
  }
  #pragma unroll
  for (int t = 0; t < 12; ++t) convL[wv][t][lane] = acc[t];

  float kc[64];
  #pragma unroll
  for (int f = 0; f < 64; ++f) kc[f] = K[f * 64 + lane];
  float bs = bias[lane];
  __syncthreads();

  #pragma unroll
  for (int t = 0; t < 12; ++t) {
    const float4* cv = (const float4*)convL[wv][t];
    float o = bs;
    #pragma unroll
    for (int i = 0; i < 16; ++i) {
      float4 c4 = cv[i];
      o += c4.x * kc[4*i] + c4.y * kc[4*i+1] + c4.z * kc[4*i+2] + c4.w * kc[4*i+3];
    }
    out[((size_t)(b * TT + t) * NN + j) * UU + lane] = o;
  }
}

// ---------------------------------------------------------------------------
extern "C" void kernel_launch(void* const* d_in, const int* in_sizes, int n_in,
                              void* d_out, int out_size, void* d_ws, size_t ws_size,
                              hipStream_t stream)
{
  const float* x    = (const float*)d_in[0];  // (B,T,N,F)
  const float* A    = (const float*)d_in[1];  // (N,N)
  const float* W1   = (const float*)d_in[2];  // (T,1)
  const float* W2   = (const float*)d_in[3];  // (F,T)
  const float* W3   = (const float*)d_in[4];  // (F,1)
  const float* Ve   = (const float*)d_in[5];  // (N,N)
  const float* be   = (const float*)d_in[6];  // (N,N)
  const float* K    = (const float*)d_in[7];  // (F,U)
  const float* bias = (const float*)d_in[8];  // (U,)
  float* out = (float*)d_out;

  char* ws = (char*)d_ws;
  float* lhs   = (float*)ws + OF_LHS;
  float* rhsS  = (float*)ws + OF_RHS;
  float* beT   = (float*)ws + OF_BET;
  float* evals = (float*)ws + OF_EVALS;
  int*      nnz  = (int*)(ws + OB_NNZ);
  int*      cidx = (int*)(ws + OB_CIDX);
  int*      ccnt = (int*)(ws + OB_CCNT);
  unsigned* colj = (unsigned*)(ws + OB_COLJ);
  unsigned short* xT = (unsigned short*)(ws + OB_XT);

  const bool use_xt = ws_size >= OB_XT + XT_BYTES;

  hipMemsetAsync(ccnt, 0, NN * sizeof(int), stream);

  // 1. lhs / rhs (+ transposed bf16 copy of x)
  k_lhs_rhs<<<dim3(BB * NN / 4), dim3(256), 0, stream>>>(
      x, W1, W2, W3, lhs, rhsS, use_xt ? xT : nullptr);
  // 2. transpose be
  k_transpose<<<dim3(NN * NN / 256), dim3(256), 0, stream>>>(be, beT);
  // 3. row index lists
  k_build_idx<<<dim3(NN), dim3(64), 0, stream>>>(A, nnz, cidx);
  // 4. column lists
  k_build_col<<<dim3(NN), dim3(64), 0, stream>>>(nnz, cidx, ccnt, colj);
  // 5. product + sigmoid + masked E
  k_product_E<<<dim3(BB, NN / MCH), dim3(256), 0, stream>>>(lhs, rhsS, beT, Ve, ccnt, colj, evals);
  // 6. softmax over slots
  k_softmax<<<dim3(BB * NN / 4), dim3(256), 0, stream>>>(nnz, evals);
  // 7. sparse conv (contiguous imm-offset bf16 gather) + v8 output GEMM
  if (use_xt)
    k_out9<<<dim3(BB * NN / 4), dim3(256), 0, stream>>>(xT, nnz, cidx, evals, K, bias, out);
  else
    k_out3f<<<dim3(BB * NN / 4), dim3(256), 0, stream>>>(x, nnz, cidx, evals, K, bias, out);
}

// Round 11
// 266.049 us; speedup vs baseline: 9.7673x; 1.0209x over previous
//
#include <hip/hip_runtime.h>
#include <hip/hip_bf16.h>
#include <cstdint>

// Problem constants
constexpr int BB = 64;    // batch
constexpr int TT = 12;    // time
constexpr int NN = 512;   // nodes
constexpr int FF = 64;    // features
constexpr int UU = 64;    // units
constexpr int MAXNZ = 128;
constexpr int MCH = 16;   // m-columns per k_product_E block

// ---------------------------------------------------------------------------
// Workspace layout (bytes):
//   floats: lhs 0 / rhs 393216f / beT 786432f / evals 1048576f
//   ints:   nnz 20971520 / cidx 20973568 / ccnt 21235712 / colj 21237760
//   xT (B,N,T,F) bf16 : 21516288, 50331648 B  (transposed bf16 copy of x)
// ---------------------------------------------------------------------------
constexpr size_t OF_LHS   = 0;
constexpr size_t OF_RHS   = 393216;
constexpr size_t OF_BET   = 786432;
constexpr size_t OF_EVALS = 1048576;
constexpr size_t OB_NNZ   = 20971520;
constexpr size_t OB_CIDX  = 20973568;
constexpr size_t OB_CCNT  = 21235712;
constexpr size_t OB_COLJ  = 21237760;
constexpr size_t OB_XT    = 21516288;
constexpr size_t XT_BYTES = (size_t)BB * NN * TT * FF * 2;  // 50331648

__device__ __forceinline__ float wred_sum(float v) {
  #pragma unroll
  for (int off = 32; off; off >>= 1) v += __shfl_xor(v, off, 64);
  return v;
}

__device__ __forceinline__ float bflo(unsigned u) {
  return __uint_as_float(u << 16);
}
__device__ __forceinline__ float bfhi(unsigned u) {
  return __uint_as_float(u & 0xFFFF0000u);
}

// ---------------------------------------------------------------------------
// Kernel 1: lhs/rhs reductions; also writes xT[b][n][t][f] (bf16 transposed
// copy of x) — xv[12] is already register-resident here.
// ---------------------------------------------------------------------------
__global__ __launch_bounds__(256) void k_lhs_rhs(
    const float* __restrict__ x, const float* __restrict__ W1,
    const float* __restrict__ W2, const float* __restrict__ W3,
    float* __restrict__ lhs, float* __restrict__ rhsS,
    unsigned short* __restrict__ xT)   // may be null
{
  int unit = blockIdx.x * 4 + (threadIdx.x >> 6);   // b*512 + n
  int lane = threadIdx.x & 63;
  int b = unit >> 9, n = unit & 511;

  const float* xb = x + ((size_t)b * TT * NN + n) * FF + lane;
  float xv[12];
  #pragma unroll
  for (int t = 0; t < 12; ++t) xv[t] = xb[(size_t)t * NN * FF];

  if (xT) {
    // xT[b][n][t][f]: per t, 64 lanes write 128 contiguous bytes
    unsigned short* xo = xT + (size_t)unit * (TT * FF) + lane;
    #pragma unroll
    for (int t = 0; t < 12; ++t) {
      __hip_bfloat16 h = __float2bfloat16(xv[t]);   // RTNE
      xo[t * FF] = *reinterpret_cast<unsigned short*>(&h);
    }
  }

  float r1 = 0.f;
  #pragma unroll
  for (int t = 0; t < 12; ++t) r1 += xv[t] * W1[t];

  float w3 = W3[lane];

  float myl = 0.f, myr = 0.f;
  #pragma unroll
  for (int t = 0; t < 12; ++t) {
    float a = r1 * W2[lane * 12 + t];
    float c = xv[t] * w3;
    a = wred_sum(a);
    c = wred_sum(c);
    if (lane == t) { myl = a; myr = c; }
  }
  if (lane < 12) {
    lhs[(size_t)unit * 12 + lane]  = myl;
    rhsS[(size_t)unit * 12 + lane] = myr;
  }
}

// ---------------------------------------------------------------------------
// Kernel 2: beT[m,k] = be[k,m]
// ---------------------------------------------------------------------------
__global__ __launch_bounds__(256) void k_transpose(
    const float* __restrict__ be, float* __restrict__ beT)
{
  int i = blockIdx.x * 256 + threadIdx.x;  // 262144 total
  int k = i >> 9, m = i & 511;
  beT[m * 512 + k] = be[i];
}

// ---------------------------------------------------------------------------
// Kernel 3: row-wise compaction of mask A (deterministic, ordered by m)
// ---------------------------------------------------------------------------
__global__ void k_build_idx(const float* __restrict__ A,
                            int* __restrict__ nnz, int* __restrict__ cidx)
{
  int j = blockIdx.x;
  int lane = threadIdx.x;  // 64 threads
  unsigned long long lt = (1ull << lane) - 1ull;
  int base = 0;
  for (int c = 0; c < 8; ++c) {
    int m = c * 64 + lane;
    bool p = A[(size_t)j * 512 + m] > 0.5f;
    unsigned long long mask = __ballot(p);
    int pos = base + __popcll(mask & lt);
    if (p && pos < MAXNZ) cidx[j * MAXNZ + pos] = m;
    base += __popcll(mask);
  }
  if (lane == 0) nnz[j] = base > MAXNZ ? MAXNZ : base;
}

// ---------------------------------------------------------------------------
// Kernel 4: column lists
// ---------------------------------------------------------------------------
__global__ void k_build_col(const int* __restrict__ nnz, const int* __restrict__ cidx,
                            int* __restrict__ ccnt, unsigned* __restrict__ colj)
{
  int j = blockIdx.x;
  int lane = threadIdx.x;
  int cnt = nnz[j];
  for (int s = lane; s < cnt; s += 64) {
    int m = cidx[j * MAXNZ + s];
    int pos = atomicAdd(&ccnt[m], 1);
    if (pos < MAXNZ) colj[m * MAXNZ + pos] = (unsigned)j | ((unsigned)s << 16);
  }
}

// ---------------------------------------------------------------------------
// Kernel 5 (v2): unchanged (16 columns/block, 16-lane entry groups)
// ---------------------------------------------------------------------------
__global__ __launch_bounds__(256) void k_product_E(
    const float* __restrict__ lhs, const float* __restrict__ rhsS,
    const float* __restrict__ beT, const float* __restrict__ Ve,
    const int* __restrict__ ccnt, const unsigned* __restrict__ colj,
    float* __restrict__ evals)
{
  int b  = blockIdx.x;   // 0..63
  int mc = blockIdx.y;   // 0..31

  __shared__ float lhsL[512 * 13];  // stride 13: conflict-free
  __shared__ float sL[4][512];
  __shared__ float rh[MCH * 12];

  int tid = threadIdx.x;
  const float* src = lhs + (size_t)b * 512 * 12;
  for (int i = tid; i < 6144; i += 256) {
    int k = i / 12, t = i - k * 12;
    lhsL[k * 13 + t] = src[i];
  }
  if (tid < MCH * 12) rh[tid] = rhsS[((size_t)b * 512 + mc * MCH) * 12 + tid];
  __syncthreads();

  int wave = tid >> 6, lane = tid & 63;
  int grp = lane >> 4, lg = lane & 15;

  for (int g = 0; g < MCH / 4; ++g) {
    if (g) __syncthreads();
    for (int i = tid; i < 4 * 512; i += 256) {
      int w = i >> 9, k = i & 511;
      int m = mc * MCH + g * 4 + w;
      float p = beT[m * 512 + k];
      const float* lr = &lhsL[k * 13];
      const float* rw = &rh[(g * 4 + w) * 12];
      #pragma unroll
      for (int t = 0; t < 12; ++t) p += lr[t] * rw[t];
      sL[w][k] = 1.0f / (1.0f + __expf(-p));
    }
    __syncthreads();

    int m = mc * MCH + g * 4 + wave;
    int cnt = ccnt[m];
    if (cnt > MAXNZ) cnt = MAXNZ;
    const float* sw = sL[wave];
    for (int e = grp; e < cnt; e += 4) {
      unsigned pk = colj[m * MAXNZ + e];
      int j = pk & 0xffff, slot = (int)(pk >> 16);
      const float* vr = Ve + (size_t)j * 512;
      float part = 0.f;
      #pragma unroll
      for (int kk = 0; kk < 32; ++kk)
        part = fmaf(vr[kk * 16 + lg], sw[kk * 16 + lg], part);
      #pragma unroll
      for (int off = 8; off; off >>= 1) part += __shfl_xor(part, off, 64);
      if (lg == 0) evals[((size_t)b * 512 + j) * MAXNZ + slot] = part;
    }
  }
}

// ---------------------------------------------------------------------------
// Kernel 6: masked softmax (unchanged)
// ---------------------------------------------------------------------------
__global__ __launch_bounds__(256) void k_softmax(
    const int* __restrict__ nnz, float* __restrict__ evals)
{
  int unit = blockIdx.x * 4 + (threadIdx.x >> 6);  // b*512 + j
  int lane = threadIdx.x & 63;
  int j = unit & 511;
  int cnt = nnz[j];
  float* ev = evals + (size_t)unit * MAXNZ;
  float v0 = lane < cnt        ? ev[lane]      : -__builtin_inff();
  float v1 = (lane + 64) < cnt ? ev[lane + 64] : -__builtin_inff();
  float mx = fmaxf(v0, v1);
  #pragma unroll
  for (int off = 32; off; off >>= 1) mx = fmaxf(mx, __shfl_xor(mx, off, 64));
  float e0 = lane < cnt        ? __expf(v0 - mx) : 0.f;
  float e1 = (lane + 64) < cnt ? __expf(v1 - mx) : 0.f;
  float s = wred_sum(e0 + e1);
  float inv = 1.0f / s;
  if (lane < cnt)        ev[lane]      = e0 * inv;
  if ((lane + 64) < cnt) ev[lane + 64] = e1 * inv;
}

// ---------------------------------------------------------------------------
// Kernel 7 (v10): wave per (b,j). Phase A identical to v9 (xT imm-offset bf16
//   gather, 2-neighbor unroll). Phase B f-TILED:
//   R10 evidence: VGPR=44 proves kc[64] never lived in registers — compiler
//   sank the 64 loop-invariant K loads into the unrolled t-loop => ~768
//   L2-hit loads + ~750 addr-adds per wave (~73% of kernel cycles).
//   Fix: tile f by 16. Per tile: kc[16] (12 reuses each, trivially fits the
//   regalloc budget) + o[12] accumulators. K loads/wave: 768 -> 64.
// XCD swizzle: grid = 8192, sbid = (bid&7)*1024 + (bid>>3) bijective.
// ---------------------------------------------------------------------------
__global__ __launch_bounds__(256) void k_out10(
    const unsigned short* __restrict__ xT,
    const int* __restrict__ nnz, const int* __restrict__ cidx,
    const float* __restrict__ evals,
    const float* __restrict__ K, const float* __restrict__ bias,
    float* __restrict__ out)
{
  int tid = threadIdx.x;
  int wv = tid >> 6, lane = tid & 63;
  int bid = blockIdx.x;
  int sbid = (bid & 7) * 1024 + (bid >> 3);  // bijective on [0,8192)
  int unit = sbid * 4 + wv;                  // b*512 + j
  int b = unit >> 9, j = unit & 511;

  __shared__ float convL[4][12][64];   // 12 KB
  __shared__ float valL[4][MAXNZ];     //  2 KB
  __shared__ int   idxL[4][MAXNZ];     //  2 KB

  int cnt = nnz[j];
  for (int s = lane; s < cnt; s += 64) {
    idxL[wv][s] = cidx[j * MAXNZ + s];
    valL[wv][s] = evals[(size_t)unit * MAXNZ + s];
  }
  // wave-private LDS + same-wave program order => no barrier needed here

  float2 acc[6];
  #pragma unroll
  for (int i = 0; i < 6; ++i) acc[i] = make_float2(0.f, 0.f);

  const unsigned* xb = reinterpret_cast<const unsigned*>(
      xT + (size_t)b * NN * (TT * FF));   // b-base, uint units (384/row)

  int s = 0;
  for (; s + 1 < cnt; s += 2) {
    int   k0 = idxL[wv][s],     k1 = idxL[wv][s + 1];
    float v0 = valL[wv][s],     v1 = valL[wv][s + 1];
    const unsigned* p0 = xb + k0 * 384 + lane;
    const unsigned* p1 = xb + k1 * 384 + lane;
    unsigned a0 = p0[0],   a1 = p0[64],  a2 = p0[128],
             a3 = p0[192], a4 = p0[256], a5 = p0[320];
    unsigned c0 = p1[0],   c1 = p1[64],  c2 = p1[128],
             c3 = p1[192], c4 = p1[256], c5 = p1[320];
    acc[0].x = fmaf(v0, bflo(a0), acc[0].x); acc[0].y = fmaf(v0, bfhi(a0), acc[0].y);
    acc[1].x = fmaf(v0, bflo(a1), acc[1].x); acc[1].y = fmaf(v0, bfhi(a1), acc[1].y);
    acc[2].x = fmaf(v0, bflo(a2), acc[2].x); acc[2].y = fmaf(v0, bfhi(a2), acc[2].y);
    acc[3].x = fmaf(v0, bflo(a3), acc[3].x); acc[3].y = fmaf(v0, bfhi(a3), acc[3].y);
    acc[4].x = fmaf(v0, bflo(a4), acc[4].x); acc[4].y = fmaf(v0, bfhi(a4), acc[4].y);
    acc[5].x = fmaf(v0, bflo(a5), acc[5].x); acc[5].y = fmaf(v0, bfhi(a5), acc[5].y);
    acc[0].x = fmaf(v1, bflo(c0), acc[0].x); acc[0].y = fmaf(v1, bfhi(c0), acc[0].y);
    acc[1].x = fmaf(v1, bflo(c1), acc[1].x); acc[1].y = fmaf(v1, bfhi(c1), acc[1].y);
    acc[2].x = fmaf(v1, bflo(c2), acc[2].x); acc[2].y = fmaf(v1, bfhi(c2), acc[2].y);
    acc[3].x = fmaf(v1, bflo(c3), acc[3].x); acc[3].y = fmaf(v1, bfhi(c3), acc[3].y);
    acc[4].x = fmaf(v1, bflo(c4), acc[4].x); acc[4].y = fmaf(v1, bfhi(c4), acc[4].y);
    acc[5].x = fmaf(v1, bflo(c5), acc[5].x); acc[5].y = fmaf(v1, bfhi(c5), acc[5].y);
  }
  if (s < cnt) {  // odd tail
    int   k0 = idxL[wv][s];
    float v0 = valL[wv][s];
    const unsigned* p0 = xb + k0 * 384 + lane;
    unsigned a0 = p0[0],   a1 = p0[64],  a2 = p0[128],
             a3 = p0[192], a4 = p0[256], a5 = p0[320];
    acc[0].x = fmaf(v0, bflo(a0), acc[0].x); acc[0].y = fmaf(v0, bfhi(a0), acc[0].y);
    acc[1].x = fmaf(v0, bflo(a1), acc[1].x); acc[1].y = fmaf(v0, bfhi(a1), acc[1].y);
    acc[2].x = fmaf(v0, bflo(a2), acc[2].x); acc[2].y = fmaf(v0, bfhi(a2), acc[2].y);
    acc[3].x = fmaf(v0, bflo(a3), acc[3].x); acc[3].y = fmaf(v0, bfhi(a3), acc[3].y);
    acc[4].x = fmaf(v0, bflo(a4), acc[4].x); acc[4].y = fmaf(v0, bfhi(a4), acc[4].y);
    acc[5].x = fmaf(v0, bflo(a5), acc[5].x); acc[5].y = fmaf(v0, bfhi(a5), acc[5].y);
  }

  // acc[i] -> t = 2i + (lane>>5), f = 2*(lane&31)
  int half = lane >> 5, fl = lane & 31;
  #pragma unroll
  for (int i = 0; i < 6; ++i)
    *(float2*)&convL[wv][2 * i + half][fl * 2] = acc[i];  // 2-way alias: free

  // Phase B, f-tiled: o[12] accumulators, kc[16] per tile (4 tiles)
  float bs = bias[lane];
  float o[12];
  #pragma unroll
  for (int t = 0; t < 12; ++t) o[t] = bs;

  __syncthreads();  // conv tiles visible across lanes

  #pragma unroll
  for (int ft = 0; ft < 4; ++ft) {
    float kc[16];
    #pragma unroll
    for (int i = 0; i < 16; ++i) kc[i] = K[(ft * 16 + i) * 64 + lane];
    #pragma unroll
    for (int t = 0; t < 12; ++t) {
      const float4* cv = (const float4*)&convL[wv][t][ft * 16];
      float4 c0 = cv[0], c1 = cv[1], c2 = cv[2], c3 = cv[3];
      o[t] += c0.x * kc[0]  + c0.y * kc[1]  + c0.z * kc[2]  + c0.w * kc[3]
            + c1.x * kc[4]  + c1.y * kc[5]  + c1.z * kc[6]  + c1.w * kc[7]
            + c2.x * kc[8]  + c2.y * kc[9]  + c2.z * kc[10] + c2.w * kc[11]
            + c3.x * kc[12] + c3.y * kc[13] + c3.z * kc[14] + c3.w * kc[15];
    }
  }

  #pragma unroll
  for (int t = 0; t < 12; ++t)
    out[((size_t)(b * TT + t) * NN + j) * UU + lane] = o[t];
}

// ---------------------------------------------------------------------------
// Kernel 7 fallback (fp32 scalar gather + f-tiled phase B) — if ws small
// ---------------------------------------------------------------------------
__global__ __launch_bounds__(256) void k_out3f(
    const float* __restrict__ x,
    const int* __restrict__ nnz, const int* __restrict__ cidx,
    const float* __restrict__ evals,
    const float* __restrict__ K, const float* __restrict__ bias,
    float* __restrict__ out)
{
  int wv = threadIdx.x >> 6, lane = threadIdx.x & 63;
  int bid = blockIdx.x;
  int sbid = (bid & 7) * 1024 + (bid >> 3);
  int unit = sbid * 4 + wv;
  int b = unit >> 9, j = unit & 511;

  __shared__ float convL[4][12][64];
  __shared__ float valL[4][MAXNZ];
  __shared__ int   idxL[4][MAXNZ];

  int cnt = nnz[j];
  for (int s = lane; s < cnt; s += 64) {
    idxL[wv][s] = cidx[j * MAXNZ + s];
    valL[wv][s] = evals[(size_t)unit * MAXNZ + s];
  }

  float acc[12];
  #pragma unroll
  for (int t = 0; t < 12; ++t) acc[t] = 0.f;

  const float* xb = x + (size_t)b * TT * NN * FF + lane;
  for (int s = 0; s < cnt; ++s) {
    float v = valL[wv][s];
    const float* xk = xb + (size_t)idxL[wv][s] * FF;
    #pragma unroll
    for (int t = 0; t < 12; ++t)
      acc[t] = fmaf(v, xk[(size_t)t * NN * FF], acc[t]);
  }
  #pragma unroll
  for (int t = 0; t < 12; ++t) convL[wv][t][lane] = acc[t];

  float bs = bias[lane];
  float o[12];
  #pragma unroll
  for (int t = 0; t < 12; ++t) o[t] = bs;
  __syncthreads();

  #pragma unroll
  for (int ft = 0; ft < 4; ++ft) {
    float kc[16];
    #pragma unroll
    for (int i = 0; i < 16; ++i) kc[i] = K[(ft * 16 + i) * 64 + lane];
    #pragma unroll
    for (int t = 0; t < 12; ++t) {
      const float4* cv = (const float4*)&convL[wv][t][ft * 16];
      float4 c0 = cv[0], c1 = cv[1], c2 = cv[2], c3 = cv[3];
      o[t] += c0.x * kc[0]  + c0.y * kc[1]  + c0.z * kc[2]  + c0.w * kc[3]
            + c1.x * kc[4]  + c1.y * kc[5]  + c1.z * kc[6]  + c1.w * kc[7]
            + c2.x * kc[8]  + c2.y * kc[9]  + c2.z * kc[10] + c2.w * kc[11]
            + c3.x * kc[12] + c3.y * kc[13] + c3.z * kc[14] + c3.w * kc[15];
    }
  }

  #pragma unroll
  for (int t = 0; t < 12; ++t)
    out[((size_t)(b * TT + t) * NN + j) * UU + lane] = o[t];
}

// ---------------------------------------------------------------------------
extern "C" void kernel_launch(void* const* d_in, const int* in_sizes, int n_in,
                              void* d_out, int out_size, void* d_ws, size_t ws_size,
                              hipStream_t stream)
{
  const float* x    = (const float*)d_in[0];  // (B,T,N,F)
  const float* A    = (const float*)d_in[1];  // (N,N)
  const float* W1   = (const float*)d_in[2];  // (T,1)
  const float* W2   = (const float*)d_in[3];  // (F,T)
  const float* W3   = (const float*)d_in[4];  // (F,1)
  const float* Ve   = (const float*)d_in[5];  // (N,N)
  const float* be   = (const float*)d_in[6];  // (N,N)
  const float* K    = (const float*)d_in[7];  // (F,U)
  const float* bias = (const float*)d_in[8];  // (U,)
  float* out = (float*)d_out;

  char* ws = (char*)d_ws;
  float* lhs   = (float*)ws + OF_LHS;
  float* rhsS  = (float*)ws + OF_RHS;
  float* beT   = (float*)ws + OF_BET;
  float* evals = (float*)ws + OF_EVALS;
  int*      nnz  = (int*)(ws + OB_NNZ);
  int*      cidx = (int*)(ws + OB_CIDX);
  int*      ccnt = (int*)(ws + OB_CCNT);
  unsigned* colj = (unsigned*)(ws + OB_COLJ);
  unsigned short* xT = (unsigned short*)(ws + OB_XT);

  const bool use_xt = ws_size >= OB_XT + XT_BYTES;

  hipMemsetAsync(ccnt, 0, NN * sizeof(int), stream);

  // 1. lhs / rhs (+ transposed bf16 copy of x)
  k_lhs_rhs<<<dim3(BB * NN / 4), dim3(256), 0, stream>>>(
      x, W1, W2, W3, lhs, rhsS, use_xt ? xT : nullptr);
  // 2. transpose be
  k_transpose<<<dim3(NN * NN / 256), dim3(256), 0, stream>>>(be, beT);
  // 3. row index lists
  k_build_idx<<<dim3(NN), dim3(64), 0, stream>>>(A, nnz, cidx);
  // 4. column lists
  k_build_col<<<dim3(NN), dim3(64), 0, stream>>>(nnz, cidx, ccnt, colj);
  // 5. product + sigmoid + masked E
  k_product_E<<<dim3(BB, NN / MCH), dim3(256), 0, stream>>>(lhs, rhsS, beT, Ve, ccnt, colj, evals);
  // 6. softmax over slots
  k_softmax<<<dim3(BB * NN / 4), dim3(256), 0, stream>>>(nnz, evals);
  // 7. sparse conv (v9 phase A) + f-tiled output GEMM
  if (use_xt)
    k_out10<<<dim3(BB * NN / 4), dim3(256), 0, stream>>>(xT, nnz, cidx, evals, K, bias, out);
  else
    k_out3f<<<dim3(BB * NN / 4), dim3(256), 0, stream>>>(x, nnz, cidx, evals, K, bias, out);
}